// Round 4
// baseline (2691.077 us; speedup 1.0000x reference)
//
#include <hip/hip_runtime.h>
#include <hip/hip_bf16.h>
#include <stdint.h>

typedef unsigned long long ull;
typedef double vd4 __attribute__((ext_vector_type(4)));
typedef __attribute__((ext_vector_type(8))) short short8;
typedef __attribute__((ext_vector_type(4))) float f32x4;

#define BATCH   16384
#define IN_DIM  784
#define INTER   1024
#define CODE    2048
#define NSTRIPE 32
#define SDIM    64
#define KNEUR   64
#define KSTR    4
#define NPAD    896   // 784 padded to 7*128 for the layer-4 MFMA tile grid

__device__ __forceinline__ float bf2f(unsigned short u) {
  return __uint_as_float(((unsigned)u) << 16);
}

// round-to-nearest-even f32 -> bf16 bits
__device__ __forceinline__ unsigned short f2bf_rn(float x) {
  unsigned u = __float_as_uint(x);
  u += 0x7FFFu + ((u >> 16) & 1u);
  return (unsigned short)(u >> 16);
}

// async global->LDS, 16B per lane (dest must be linear in lane order)
__device__ __forceinline__ void gld_lds16(const void* g, void* l) {
  __builtin_amdgcn_global_load_lds(
      (__attribute__((address_space(1))) void*)(g),
      (__attribute__((address_space(3))) void*)(l), 16, 0, 0);
}

// ---------------------------------------------------------------------------
// Input dtype detector (insurance): flag=1 => inputs are bf16.
// ---------------------------------------------------------------------------
__global__ void detect_dtype(const unsigned* __restrict__ w1raw, int* __restrict__ flag) {
  __shared__ unsigned cnt;
  if (threadIdx.x == 0) cnt = 0u;
  __syncthreads();
  unsigned c = 0;
  for (int i = threadIdx.x; i < 512; i += 256) {
    unsigned e = (w1raw[i] >> 7) & 0xFFu;
    if (e >= 100u && e <= 126u) ++c;
  }
  atomicAdd(&cnt, c);
  __syncthreads();
  if (threadIdx.x == 0) *flag = (cnt > 256u) ? 1 : 0;
}

// ---------------------------------------------------------------------------
// One-time: W2 [2048][1024] (f32 or bf16) -> f64.
// ---------------------------------------------------------------------------
__global__ __launch_bounds__(256) void convert_w2_f64(
    const void* __restrict__ W2v, double* __restrict__ W2d,
    const int* __restrict__ dflag)
{
  const int f = *dflag;
  const size_t base = (size_t)blockIdx.x * INTER + 4u * threadIdx.x;
  double v0, v1, v2, v3;
  if (f) {
    ushort4 r = *(const ushort4*)((const unsigned short*)W2v + base);
    v0 = (double)bf2f(r.x); v1 = (double)bf2f(r.y);
    v2 = (double)bf2f(r.z); v3 = (double)bf2f(r.w);
  } else {
    float4 r = *(const float4*)((const float*)W2v + base);
    v0 = r.x; v1 = r.y; v2 = r.z; v3 = r.w;
  }
  W2d[base + 0] = v0; W2d[base + 1] = v1;
  W2d[base + 2] = v2; W2d[base + 3] = v3;
}

// ---------------------------------------------------------------------------
// Layer-2 FP64 MFMA GEMM, m97-style: A [CH][1024] f64 (h64), B [2048][1024]
// f64 (pre-converted W2), C = relu(A·B^T + b2) [CH][2048] f64.
// BM=BN=128, BK=16, 256 thr / 4 waves (2x2), each wave 64x64 = 4x4 of
// 16x16x4 f64 MFMA tiles. Staging via global_load_lds (16B = 2 doubles/lane),
// LDS [m][k] with k ^= 2*(m&7) XOR swizzle applied on the GLOBAL source
// (linear DMA dest) and on the fragment read -> 2-way banks (free) instead
// of the 16-way stride-128B conflict.
// ---------------------------------------------------------------------------
__global__ __launch_bounds__(256) void gemm2_f64_mfma128(
    const double* __restrict__ A, const double* __restrict__ B,
    const void* __restrict__ biasv, double* __restrict__ C,
    const int* __restrict__ dflag)
{
  __shared__ double As[128 * 16];   // 16 KB
  __shared__ double Bs[128 * 16];   // 16 KB
  const int f = *dflag;
  const int tid  = threadIdx.x;
  const int lane = tid & 63;
  const int wave = tid >> 6;                  // 0..3
  const int wr = wave >> 1, wc = wave & 1;    // 2x2 wave grid of 64x64
  const int lm = lane & 15, lq = lane >> 4;
  const int m0 = blockIdx.y * 128, n0 = blockIdx.x * 128;
  const int axor = (lm & 7) << 1;             // read-side k-xor (m&7 == lm&7)

  vd4 acc[4][4];
#pragma unroll
  for (int i = 0; i < 4; ++i)
#pragma unroll
    for (int j = 0; j < 4; ++j)
#pragma unroll
      for (int r = 0; r < 4; ++r) acc[i][j][r] = 0.0;

  for (int k0 = 0; k0 < INTER; k0 += 16) {
    // stage A/B: 1024 chunks of 16B each matrix; chunk c -> LDS bytes 16c,
    // logical (m = c>>3, kswz = (c&7)*2), global k = kswz ^ (2*(m&7)).
#pragma unroll
    for (int i = 0; i < 4; ++i) {
      const int c  = i * 256 + tid;
      const int m  = c >> 3;
      const int kk = ((c & 7) << 1) ^ ((m & 7) << 1);
      gld_lds16(A + (size_t)(m0 + m) * INTER + (k0 + kk), (char*)As + c * 16);
      gld_lds16(B + (size_t)(n0 + m) * INTER + (k0 + kk), (char*)Bs + c * 16);
    }
    __syncthreads();   // compiler drains vmcnt before s_barrier

#pragma unroll
    for (int ks = 0; ks < 4; ++ks) {
      const int kx = (ks * 4 + lq) ^ axor;
      double a[4], b[4];
#pragma unroll
      for (int i = 0; i < 4; ++i) {
        a[i] = As[(wr * 64 + i * 16 + lm) * 16 + kx];
        b[i] = Bs[(wc * 64 + i * 16 + lm) * 16 + kx];
      }
#pragma unroll
      for (int i = 0; i < 4; ++i)
#pragma unroll
        for (int j = 0; j < 4; ++j)
          acc[i][j] = __builtin_amdgcn_mfma_f64_16x16x4f64(a[i], b[j], acc[i][j], 0, 0, 0);
    }
    __syncthreads();
  }

  // epilogue: D col = lane&15, row = (lane>>4)*4 + reg (same as 64-tile kernel)
#pragma unroll
  for (int j = 0; j < 4; ++j) {
    const int col = n0 + wc * 64 + j * 16 + lm;
    const double bv = f ? (double)bf2f(((const unsigned short*)biasv)[col])
                        : (double)((const float*)biasv)[col];
#pragma unroll
    for (int i = 0; i < 4; ++i) {
      const int row = m0 + wr * 64 + i * 16 + lq * 4;
#pragma unroll
      for (int r = 0; r < 4; ++r)
        C[(size_t)(row + r) * CODE + col] = fmax(acc[i][j][r] + bv, 0.0);
    }
  }
}

// ---------------------------------------------------------------------------
// FP64 MFMA GEMM NT (layer 1): C = relu(A[arow0+m,:]·B[n,:] + bias[n]) f64.
// 64x64 tile, 4 waves. A/B converted inline (x is f32/bf16).
// ---------------------------------------------------------------------------
template<bool A_IS_F64>
__global__ __launch_bounds__(256) void gemm_nt_f64_mfma(
    const void* __restrict__ Av, const void* __restrict__ Bv,
    const void* __restrict__ biasv, double* __restrict__ C,
    int N, int K, int arow0, const int* __restrict__ dflag)
{
  __shared__ double As[16][64];   // [k][m]
  __shared__ double Bs[16][64];   // [k][n]
  const int f = *dflag;
  const int tid  = threadIdx.x;
  const int lane = tid & 63;
  const int wave = tid >> 6;            // 0..3
  const int wr = wave >> 1, wc = wave & 1;
  const int m0 = blockIdx.y * 64, n0 = blockIdx.x * 64;

  const int srow = tid >> 2;            // 0..63 staging row
  const int sk4  = (tid & 3) << 2;      // 0,4,8,12

  vd4 acc[2][2];
#pragma unroll
  for (int i = 0; i < 2; ++i)
#pragma unroll
    for (int j = 0; j < 2; ++j)
#pragma unroll
      for (int r = 0; r < 4; ++r) acc[i][j][r] = 0.0;

  const int lm = lane & 15;             // m/n within 16-tile
  const int lq = lane >> 4;             // k within 4-chunk

  for (int k0 = 0; k0 < K; k0 += 16) {
    // ---- stage A tile (64 rows x 16 k) ----
    if (A_IS_F64) {
      const double* Ap = (const double*)Av + (size_t)(arow0 + m0 + srow) * K + (k0 + sk4);
      As[sk4 + 0][srow] = Ap[0]; As[sk4 + 1][srow] = Ap[1];
      As[sk4 + 2][srow] = Ap[2]; As[sk4 + 3][srow] = Ap[3];
    } else if (f) {
      ushort4 t = *(const ushort4*)((const unsigned short*)Av +
                   (size_t)(arow0 + m0 + srow) * K + (k0 + sk4));
      As[sk4 + 0][srow] = (double)bf2f(t.x); As[sk4 + 1][srow] = (double)bf2f(t.y);
      As[sk4 + 2][srow] = (double)bf2f(t.z); As[sk4 + 3][srow] = (double)bf2f(t.w);
    } else {
      float4 t = *(const float4*)((const float*)Av +
                  (size_t)(arow0 + m0 + srow) * K + (k0 + sk4));
      As[sk4 + 0][srow] = (double)t.x; As[sk4 + 1][srow] = (double)t.y;
      As[sk4 + 2][srow] = (double)t.z; As[sk4 + 3][srow] = (double)t.w;
    }
    // ---- stage B tile (64 rows x 16 k) ----
    if (f) {
      ushort4 t = *(const ushort4*)((const unsigned short*)Bv +
                   (size_t)(n0 + srow) * K + (k0 + sk4));
      Bs[sk4 + 0][srow] = (double)bf2f(t.x); Bs[sk4 + 1][srow] = (double)bf2f(t.y);
      Bs[sk4 + 2][srow] = (double)bf2f(t.z); Bs[sk4 + 3][srow] = (double)bf2f(t.w);
    } else {
      float4 t = *(const float4*)((const float*)Bv +
                  (size_t)(n0 + srow) * K + (k0 + sk4));
      Bs[sk4 + 0][srow] = (double)t.x; Bs[sk4 + 1][srow] = (double)t.y;
      Bs[sk4 + 2][srow] = (double)t.z; Bs[sk4 + 3][srow] = (double)t.w;
    }
    __syncthreads();

#pragma unroll
    for (int ks = 0; ks < 4; ++ks) {
      const int kk = ks * 4 + lq;
      double a0 = As[kk][wr * 32 + lm];
      double a1 = As[kk][wr * 32 + 16 + lm];
      double b0 = Bs[kk][wc * 32 + lm];
      double b1 = Bs[kk][wc * 32 + 16 + lm];
      acc[0][0] = __builtin_amdgcn_mfma_f64_16x16x4f64(a0, b0, acc[0][0], 0, 0, 0);
      acc[0][1] = __builtin_amdgcn_mfma_f64_16x16x4f64(a0, b1, acc[0][1], 0, 0, 0);
      acc[1][0] = __builtin_amdgcn_mfma_f64_16x16x4f64(a1, b0, acc[1][0], 0, 0, 0);
      acc[1][1] = __builtin_amdgcn_mfma_f64_16x16x4f64(a1, b1, acc[1][1], 0, 0, 0);
    }
    __syncthreads();
  }

  // ---- epilogue: D col = lane&15, row = (lane>>4)*4 + reg ----
#pragma unroll
  for (int tc = 0; tc < 2; ++tc) {
    const int col = n0 + wc * 32 + tc * 16 + lm;
    const double bv = f ? (double)bf2f(((const unsigned short*)biasv)[col])
                        : (double)((const float*)biasv)[col];
#pragma unroll
    for (int tr = 0; tr < 2; ++tr) {
#pragma unroll
      for (int r = 0; r < 4; ++r) {
        const int row = m0 + wr * 32 + tr * 16 + lq * 4 + r;
        C[(size_t)row * N + col] = fmax(acc[tr][tc][r] + bv, 0.0);
      }
    }
  }
}

// ---------------------------------------------------------------------------
// One-time: split W4 [784][1024] (f32 or bf16) into bf16 hi|lo pairs,
// padded to 896 rows (pad rows zeroed).  B2 layout: [896][2048] ushort,
// cols 0..1023 = hi(W4[n][k]), cols 1024..2047 = lo(W4[n][k]).
// ---------------------------------------------------------------------------
__global__ __launch_bounds__(256) void convert_w4(
    const void* __restrict__ W4v, unsigned short* __restrict__ B2,
    const int* __restrict__ dflag)
{
  const int f = *dflag;
  const int n = blockIdx.x;            // 0..895
  const int t = threadIdx.x;           // 4 elems each
  ushort4 hi, lo;
  hi.x = hi.y = hi.z = hi.w = 0;
  lo.x = lo.y = lo.z = lo.w = 0;
  if (n < IN_DIM) {
    float v0, v1, v2, v3;
    if (f) {
      ushort4 r = *(const ushort4*)((const unsigned short*)W4v + (size_t)n * INTER + 4 * t);
      v0 = bf2f(r.x); v1 = bf2f(r.y); v2 = bf2f(r.z); v3 = bf2f(r.w);
    } else {
      float4 r = *(const float4*)((const float*)W4v + (size_t)n * INTER + 4 * t);
      v0 = r.x; v1 = r.y; v2 = r.z; v3 = r.w;
    }
    hi.x = f2bf_rn(v0); lo.x = f2bf_rn(v0 - bf2f(hi.x));
    hi.y = f2bf_rn(v1); lo.y = f2bf_rn(v1 - bf2f(hi.y));
    hi.z = f2bf_rn(v2); lo.z = f2bf_rn(v2 - bf2f(hi.z));
    hi.w = f2bf_rn(v3); lo.w = f2bf_rn(v3 - bf2f(hi.w));
  }
  *(ushort4*)(B2 + (size_t)n * 2048 + 4 * t) = hi;
  *(ushort4*)(B2 + (size_t)n * 2048 + 1024 + 4 * t) = lo;
}

// ---------------------------------------------------------------------------
// Layer-4 GEMM via bf16 MFMA with hi/lo split-K emulation (~f32 accuracy).
// 128x128 tile, BK=32, 4 waves, 16x16x32 MFMA, global_load_lds staging.
// ---------------------------------------------------------------------------
__global__ __launch_bounds__(256) void gemm_l4_bf16(
    const unsigned short* __restrict__ A2,   // [CH][2048] hi|lo
    const unsigned short* __restrict__ B2,   // [896][2048] hi|lo (pad zeroed)
    const void* __restrict__ biasv, float* __restrict__ Cout,
    int crow0, const int* __restrict__ dflag)
{
  __shared__ unsigned short As[128 * 32];    // 8 KB, rows of 32 bf16 (64 B)
  __shared__ unsigned short Bs[128 * 32];    // 8 KB
  const int f = *dflag;
  const int tid  = threadIdx.x;
  const int lane = tid & 63;
  const int wave = tid >> 6;                 // 0..3
  const int wr = wave >> 1, wc = wave & 1;   // 2x2 wave grid of 64x64
  const int lm = lane & 15, lg = lane >> 4;
  const int m0 = blockIdx.y * 128, n0 = blockIdx.x * 128;

  f32x4 acc[4][4];
#pragma unroll
  for (int i = 0; i < 4; ++i)
#pragma unroll
    for (int j = 0; j < 4; ++j)
#pragma unroll
      for (int r = 0; r < 4; ++r) acc[i][j][r] = 0.0f;

  const char* a2b = (const char*)A2;
  const char* b2b = (const char*)B2;

  for (int kt = 0; kt < 96; ++kt) {
    const int s   = kt >> 5;                 // segment 0,1,2
    const int kin = (kt & 31) << 5;          // 0..992
    const int ka  = ((s == 1) ? 1024 : 0) + kin;   // A half: lo only in seg 1
    const int kb  = ((s == 2) ? 1024 : 0) + kin;   // B half: lo only in seg 2
#pragma unroll
    for (int i = 0; i < 2; ++i) {
      const int c   = i * 256 + tid;         // chunk id
      const int row = c >> 2;                // 0..127
      const int cb  = (c & 3) * 16;          // byte within 64B row
      gld_lds16(a2b + ((size_t)(m0 + row) * 4096 + (size_t)(ka * 2 + cb)),
                (char*)As + c * 16);
      gld_lds16(b2b + ((size_t)(n0 + row) * 4096 + (size_t)(kb * 2 + cb)),
                (char*)Bs + c * 16);
    }
    __syncthreads();                         // drains vmcnt before barrier

    short8 a[4], b[4];
#pragma unroll
    for (int i = 0; i < 4; ++i) {
      a[i] = *(const short8*)((const char*)As + (wr * 64 + i * 16 + lm) * 64 + lg * 16);
      b[i] = *(const short8*)((const char*)Bs + (wc * 64 + i * 16 + lm) * 64 + lg * 16);
    }
#pragma unroll
    for (int i = 0; i < 4; ++i)
#pragma unroll
      for (int j = 0; j < 4; ++j)
        acc[i][j] = __builtin_amdgcn_mfma_f32_16x16x32_bf16(a[i], b[j], acc[i][j], 0, 0, 0);
    __syncthreads();
  }

  // ---- epilogue: D col = lane&15, row = (lane>>4)*4 + reg ----
#pragma unroll
  for (int j = 0; j < 4; ++j) {
    const int col = n0 + wc * 64 + j * 16 + lm;
    if (col < IN_DIM) {
      const float bv = f ? bf2f(((const unsigned short*)biasv)[col])
                         : ((const float*)biasv)[col];
#pragma unroll
      for (int i = 0; i < 4; ++i) {
        const int row0 = crow0 + m0 + wr * 64 + i * 16 + lg * 4;
#pragma unroll
        for (int r = 0; r < 4; ++r)
          Cout[(size_t)(row0 + r) * IN_DIM + col] = fmaxf(acc[i][j][r] + bv, 0.0f);
      }
    }
  }
}

// ---------------------------------------------------------------------------
// Transpose W3 [1024][2048] -> W3T fp32 [2048][1024] for coalesced gather.
// ---------------------------------------------------------------------------
__global__ __launch_bounds__(256) void transpose_w3(
    const void* __restrict__ W3v, float* __restrict__ W3T, const int* __restrict__ dflag)
{
  __shared__ float tile[32][33];
  const int f = *dflag;
  const int tx = threadIdx.x & 31, ty = threadIdx.x >> 5;  // 32 x 8
  const int c0 = blockIdx.x * 32;
  const int r0 = blockIdx.y * 32;
#pragma unroll
  for (int i = 0; i < 32; i += 8) {
    size_t off = (size_t)(r0 + ty + i) * CODE + (c0 + tx);
    tile[ty + i][tx] = f ? bf2f(((const unsigned short*)W3v)[off])
                         : ((const float*)W3v)[off];
  }
  __syncthreads();
#pragma unroll
  for (int i = 0; i < 32; i += 8)
    W3T[(size_t)(c0 + ty + i) * INTER + (r0 + tx)] = tile[tx][ty + i];
}

// ---------------------------------------------------------------------------
// Block scans (256 threads).
// ---------------------------------------------------------------------------
__device__ __forceinline__ unsigned scan256_incl(unsigned x, unsigned* buf, int tid) {
  __syncthreads();
  buf[tid] = x; __syncthreads();
  for (int off = 1; off < 256; off <<= 1) {
    unsigned add = (tid >= off) ? buf[tid - off] : 0u;
    __syncthreads();
    x += add; buf[tid] = x;
    __syncthreads();
  }
  return x;
}
__device__ __forceinline__ unsigned scan256_suffix(unsigned x, unsigned* buf, int tid) {
  __syncthreads();
  buf[tid] = x; __syncthreads();
  for (int off = 1; off < 256; off <<= 1) {
    unsigned add = (tid + off < 256) ? buf[tid + off] : 0u;
    __syncthreads();
    x += add; buf[tid] = x;
    __syncthreads();
  }
  return x;
}

// ---------------------------------------------------------------------------
// FP64 per-row top-64 radix select (44-bit key, ties lowest-index-first),
// fp64 stripe means, top-4 stripes, compaction to (f32 val, idx, nnz).
// ---------------------------------------------------------------------------
__global__ __launch_bounds__(256) void topk_compact_f64(
    const double* __restrict__ C, float* __restrict__ ovals,
    int* __restrict__ oidxs, int* __restrict__ onnz)
{
  __shared__ double v[CODE];            // 16 KB
  __shared__ unsigned hist[CODE];       // 8 KB
  __shared__ unsigned sbuf[256];
  __shared__ unsigned sres0, sres1, sres3;
  __shared__ int sres2;
  __shared__ double savg[NSTRIPE];
  const int tid = threadIdx.x;
  const int row = blockIdx.x;

  const double2* c2 = (const double2*)(C + (size_t)row * CODE);
#pragma unroll
  for (int i = 0; i < 4; ++i)
    ((double2*)v)[tid + 256 * i] = c2[tid + 256 * i];
  __syncthreads();

  ull u[8];
#pragma unroll
  for (int i = 0; i < 8; ++i) u[i] = __double_as_longlong(v[tid * 8 + i]);

  const int shifts[4] = {52, 41, 30, 19};
  unsigned kr = KNEUR;
  ull prefix = 0ull, pmask = 0ull;
  bool tz = false;

  for (int p = 0; p < 4; ++p) {
    const int sh = shifts[p];
    for (int i = tid; i < CODE; i += 256) hist[i] = 0u;
    __syncthreads();
#pragma unroll
    for (int i = 0; i < 8; ++i)
      if (u[i] != 0ull && (u[i] & pmask) == prefix)
        atomicAdd(&hist[(unsigned)((u[i] >> sh) & 2047ull)], 1u);
    __syncthreads();
    unsigned csum = 0u;
#pragma unroll
    for (int j = 0; j < 8; ++j) csum += hist[tid * 8 + j];
    unsigned sc = scan256_suffix(csum, sbuf, tid);
    unsigned scn = (tid < 255) ? sbuf[tid + 1] : 0u;
    if (p == 0 && tid == 0) sres2 = (sc < kr) ? 1 : 0;
    if (sc >= kr && scn < kr) {
      unsigned cum = scn;
      for (int b = 7; b >= 0; --b) {
        unsigned hb = hist[tid * 8 + b];
        if (cum + hb >= kr) { sres0 = (unsigned)(tid * 8 + b); sres1 = cum; break; }
        cum += hb;
      }
    }
    __syncthreads();
    if (p == 0 && sres2) { tz = true; break; }
    kr -= sres1;
    prefix |= ((ull)sres0) << sh;
    pmask  |= 2047ull << sh;
    __syncthreads();
  }

  const ull tkey = tz ? 0ull : (prefix >> 19);

  unsigned gt = 0u, eq = 0u;
#pragma unroll
  for (int i = 0; i < 8; ++i) {
    ull k = u[i] >> 19;
    gt += (k > tkey) ? 1u : 0u;
    eq += (k == tkey) ? 1u : 0u;
  }
  unsigned eqincl = scan256_incl(eq, sbuf, tid);
  unsigned eqbase = eqincl - eq;
  (void)scan256_incl(gt, sbuf, tid);
  unsigned total_gt = sbuf[255];
  unsigned need_eq = KNEUR - total_gt;
  unsigned er = eqbase;
#pragma unroll
  for (int i = 0; i < 8; ++i) {
    ull k = u[i] >> 19;
    bool sel = (k > tkey);
    if (k == tkey) { sel = (er < need_eq); ++er; }
    if (!sel) v[tid * 8 + i] = 0.0;
  }
  __syncthreads();

  if (tid < NSTRIPE) {
    const double* sv = v + tid * SDIM;
    double r0 = sv[0], r1 = sv[1], r2 = sv[2], r3 = sv[3],
           r4 = sv[4], r5 = sv[5], r6 = sv[6], r7 = sv[7];
    for (int i = 8; i < SDIM; i += 8) {
      r0 += sv[i + 0]; r1 += sv[i + 1]; r2 += sv[i + 2]; r3 += sv[i + 3];
      r4 += sv[i + 4]; r5 += sv[i + 5]; r6 += sv[i + 6]; r7 += sv[i + 7];
    }
    savg[tid] = (((r0 + r1) + (r2 + r3)) + ((r4 + r5) + (r6 + r7))) * 0.015625;
  }
  __syncthreads();
  if (tid == 0) {
    unsigned sm = 0u;
    for (int it = 0; it < KSTR; ++it) {
      double best = -1.0; int bi = 0;
      for (int s = 0; s < NSTRIPE; ++s)
        if (!((sm >> s) & 1u) && savg[s] > best) { best = savg[s]; bi = s; }
      sm |= (1u << bi);
    }
    sres3 = sm;
  }
  __syncthreads();
  const unsigned sm = sres3;

  const bool son = ((sm >> (tid >> 3)) & 1u) != 0u;
  double mv[8];
  unsigned act = 0u, cnt = 0u;
#pragma unroll
  for (int i = 0; i < 8; ++i) {
    mv[i] = v[tid * 8 + i];
    bool a = son && (mv[i] != 0.0);
    act |= (a ? 1u : 0u) << i;
    cnt += a ? 1u : 0u;
  }
  unsigned cincl = scan256_incl(cnt, sbuf, tid);
  unsigned pos = cincl - cnt;
  float* vrow = ovals + (size_t)row * KNEUR;
  int* irow = oidxs + (size_t)row * KNEUR;
#pragma unroll
  for (int i = 0; i < 8; ++i) {
    if ((act >> i) & 1u) {
      vrow[pos] = (float)mv[i];
      irow[pos] = tid * 8 + i;
      ++pos;
    }
  }
  if (tid == 255) onnz[row] = (int)cincl;
}

// ---------------------------------------------------------------------------
// Sparse decode (fp32): d[row,:] = relu(b3 + sum_j val_j * W3T[idx_j,:]).
// Epilogue writes d as bf16 hi|lo pairs (A2 [CH][2048]) for layer 4.
// ---------------------------------------------------------------------------
__global__ __launch_bounds__(256) void sparse_decode(
    const float* __restrict__ W3T, const void* __restrict__ b3v,
    const float* __restrict__ vals, const int* __restrict__ idxs,
    const int* __restrict__ nnz, unsigned short* __restrict__ A2,
    const int* __restrict__ dflag)
{
  __shared__ float sv[KNEUR];
  __shared__ int si[KNEUR];
  __shared__ int scnt;
  const int f = *dflag;
  const int tid = threadIdx.x;
  const int row = blockIdx.x;
  if (tid == 0) scnt = nnz[row];
  if (tid < KNEUR) {
    sv[tid] = vals[(size_t)row * KNEUR + tid];
    si[tid] = idxs[(size_t)row * KNEUR + tid];
  }
  __syncthreads();
  const int cnt = scnt;
  float4 acc;
  if (f) {
    const unsigned short* b3b = (const unsigned short*)b3v;
    acc.x = bf2f(b3b[4 * tid + 0]); acc.y = bf2f(b3b[4 * tid + 1]);
    acc.z = bf2f(b3b[4 * tid + 2]); acc.w = bf2f(b3b[4 * tid + 3]);
  } else {
    acc = ((const float4*)b3v)[tid];
  }
  for (int j = 0; j < cnt; ++j) {
    const float vv = sv[j];
    const float4 w = ((const float4*)(W3T + (size_t)si[j] * INTER))[tid];
    acc.x = fmaf(vv, w.x, acc.x);
    acc.y = fmaf(vv, w.y, acc.y);
    acc.z = fmaf(vv, w.z, acc.z);
    acc.w = fmaf(vv, w.w, acc.w);
  }
  acc.x = fmaxf(acc.x, 0.f); acc.y = fmaxf(acc.y, 0.f);
  acc.z = fmaxf(acc.z, 0.f); acc.w = fmaxf(acc.w, 0.f);

  ushort4 hi, lo;
  hi.x = f2bf_rn(acc.x); lo.x = f2bf_rn(acc.x - bf2f(hi.x));
  hi.y = f2bf_rn(acc.y); lo.y = f2bf_rn(acc.y - bf2f(hi.y));
  hi.z = f2bf_rn(acc.z); lo.z = f2bf_rn(acc.z - bf2f(hi.z));
  hi.w = f2bf_rn(acc.w); lo.w = f2bf_rn(acc.w - bf2f(hi.w));
  *(ushort4*)(A2 + (size_t)row * 2048 + 4 * tid) = hi;
  *(ushort4*)(A2 + (size_t)row * 2048 + 1024 + 4 * tid) = lo;
}

// ---------------------------------------------------------------------------
extern "C" void kernel_launch(void* const* d_in, const int* in_sizes, int n_in,
                              void* d_out, int out_size, void* d_ws, size_t ws_size,
                              hipStream_t stream)
{
  const void* x  = d_in[0];
  const void* W1 = d_in[1];
  const void* b1 = d_in[2];
  const void* W2 = d_in[3];
  const void* b2 = d_in[4];
  const void* W3 = d_in[5];
  const void* b3 = d_in[6];
  const void* W4 = d_in[7];
  const void* b4 = d_in[8];

  // layout: [flag 256B][W3T 8MB][B2 896*2048*2][W2d 16MB]
  //         [h64 CH*8K (A2 overlays)][c64 CH*16K][cv][ci][cn]
  const size_t W3T_BYTES = (size_t)CODE * INTER * 4;
  const size_t B2_BYTES  = (size_t)NPAD * 2048 * 2;
  const size_t W2D_BYTES = (size_t)CODE * INTER * 8;
  int CH = BATCH;
  while (CH > 128) {
    size_t need = 256 + W3T_BYTES + B2_BYTES + W2D_BYTES +
                  (size_t)CH * (8192 + 16384 + 256 + 256 + 4);
    if (need <= ws_size) break;
    CH >>= 1;
  }
  char*   w    = (char*)d_ws;
  int*    flag = (int*)w;
  float*  W3T  = (float*)(w + 256);
  unsigned short* B2w = (unsigned short*)(w + 256 + W3T_BYTES);
  double* W2d  = (double*)(w + 256 + W3T_BYTES + B2_BYTES);
  char*   p    = w + 256 + W3T_BYTES + B2_BYTES + W2D_BYTES;
  double* h64  = (double*)p;                                 // CH*1024 f64
  unsigned short* A2 = (unsigned short*)p;                   // overlays h64 (dead by then)
  double* c64  = (double*)(p + (size_t)CH * 8192);           // CH*2048 f64
  float*  cv   = (float*)(p + (size_t)CH * 24576);           // CH*64 f32
  int*    ci   = (int*)  (p + (size_t)CH * 24576 + (size_t)CH * 256);
  int*    cn   = (int*)  (p + (size_t)CH * 24576 + (size_t)CH * 512);

  detect_dtype<<<1, 256, 0, stream>>>((const unsigned*)W1, flag);
  transpose_w3<<<dim3(CODE / 32, INTER / 32), 256, 0, stream>>>(W3, W3T, flag);
  convert_w4<<<NPAD, 256, 0, stream>>>(W4, B2w, flag);
  convert_w2_f64<<<CODE, 256, 0, stream>>>(W2, W2d, flag);

  for (int r0 = 0; r0 < BATCH; r0 += CH) {
    // h = relu(x @ W1^T + b1) in f64   [CH, 1024], K=784  (MFMA f64, 64-tile)
    gemm_nt_f64_mfma<false><<<dim3(INTER / 64, CH / 64), 256, 0, stream>>>(
        x, W1, b1, h64, INTER, IN_DIM, r0, flag);

    // c = relu(h @ W2^T + b2) in f64   [CH, 2048], K=1024  (128-tile DMA MFMA)
    gemm2_f64_mfma128<<<dim3(CODE / 128, CH / 128), 256, 0, stream>>>(
        h64, W2d, b2, c64, flag);

    // exact top-64 + stripe top-4 on f64 values -> compact sparse code
    topk_compact_f64<<<CH, 256, 0, stream>>>(c64, cv, ci, cn);

    // d = relu(c_sparse @ W3^T + b3) -> bf16 hi|lo split (overlays h64)
    sparse_decode<<<CH, 256, 0, stream>>>(W3T, b3, cv, ci, cn, A2, flag);

    // out[r0:r0+CH] = relu(d @ W4^T + b4) via bf16 split-K MFMA, f32 out
    gemm_l4_bf16<<<dim3(NPAD / 128, CH / 128), 256, 0, stream>>>(
        A2, B2w, b4, (float*)d_out, r0, flag);
  }
}

// Round 10
// 2138.727 us; speedup vs baseline: 1.2583x; 1.2583x over previous
//
#include <hip/hip_runtime.h>
#include <hip/hip_bf16.h>
#include <stdint.h>

typedef unsigned long long ull;
typedef double vd4 __attribute__((ext_vector_type(4)));
typedef __attribute__((ext_vector_type(8))) short short8;
typedef __attribute__((ext_vector_type(4))) float f32x4;

#define BATCH   16384
#define IN_DIM  784
#define INTER   1024
#define CODE    2048
#define NSTRIPE 32
#define SDIM    64
#define KNEUR   64
#define KSTR    4
#define NPAD    896   // 784 padded to 7*128 for the layer-4 MFMA tile grid

__device__ __forceinline__ float bf2f(unsigned short u) {
  return __uint_as_float(((unsigned)u) << 16);
}

// round-to-nearest-even f32 -> bf16 bits
__device__ __forceinline__ unsigned short f2bf_rn(float x) {
  unsigned u = __float_as_uint(x);
  u += 0x7FFFu + ((u >> 16) & 1u);
  return (unsigned short)(u >> 16);
}

// async global->LDS, 16B per lane (dest must be linear in lane order)
__device__ __forceinline__ void gld_lds16(const void* g, void* l) {
  __builtin_amdgcn_global_load_lds(
      (__attribute__((address_space(1))) void*)(g),
      (__attribute__((address_space(3))) void*)(l), 16, 0, 0);
}

// ---------------------------------------------------------------------------
// Input dtype detector (insurance): flag=1 => inputs are bf16.
// ---------------------------------------------------------------------------
__global__ void detect_dtype(const unsigned* __restrict__ w1raw, int* __restrict__ flag) {
  __shared__ unsigned cnt;
  if (threadIdx.x == 0) cnt = 0u;
  __syncthreads();
  unsigned c = 0;
  for (int i = threadIdx.x; i < 512; i += 256) {
    unsigned e = (w1raw[i] >> 7) & 0xFFu;
    if (e >= 100u && e <= 126u) ++c;
  }
  atomicAdd(&cnt, c);
  __syncthreads();
  if (threadIdx.x == 0) *flag = (cnt > 256u) ? 1 : 0;
}

// ---------------------------------------------------------------------------
// One-time: W2 [2048][1024] (f32 or bf16) -> f64.
// ---------------------------------------------------------------------------
__global__ __launch_bounds__(256) void convert_w2_f64(
    const void* __restrict__ W2v, double* __restrict__ W2d,
    const int* __restrict__ dflag)
{
  const int f = *dflag;
  const size_t base = (size_t)blockIdx.x * INTER + 4u * threadIdx.x;
  double v0, v1, v2, v3;
  if (f) {
    ushort4 r = *(const ushort4*)((const unsigned short*)W2v + base);
    v0 = (double)bf2f(r.x); v1 = (double)bf2f(r.y);
    v2 = (double)bf2f(r.z); v3 = (double)bf2f(r.w);
  } else {
    float4 r = *(const float4*)((const float*)W2v + base);
    v0 = r.x; v1 = r.y; v2 = r.z; v3 = r.w;
  }
  W2d[base + 0] = v0; W2d[base + 1] = v1;
  W2d[base + 2] = v2; W2d[base + 3] = v3;
}

// ---------------------------------------------------------------------------
// Layer-2 FP64 MFMA GEMM v2 (occupancy-fixed): A [CH][1024] f64 (h64),
// B [2048][1024] f64 (pre-converted W2), C = relu(A·B^T + b2) [CH][2048].
// BM=64, BN=128, BK=16, 256 thr / 4 waves (2x2 grid), wave tile 32x64 =
// 2x4 of 16x16x4 f64 MFMA -> acc = 64 regs/lane (v1's 4x4 = 128 regs
// collapsed occupancy to 1 wave/SIMD). launch_bounds(256,3): 3 blocks/CU.
// Staging via global_load_lds (16B = 2 doubles/lane), LDS [m][k] with
// k ^= 2*(m&7) XOR swizzle applied on the GLOBAL source (linear DMA dest)
// and on the fragment read -> 2-way banks (free). Per-output K-order is
// identical to v1/the 64-tile kernel -> bitwise-identical C.
// ---------------------------------------------------------------------------
__global__ __launch_bounds__(256, 3) void gemm2_f64_v2(
    const double* __restrict__ A, const double* __restrict__ B,
    const void* __restrict__ biasv, double* __restrict__ C,
    const int* __restrict__ dflag)
{
  __shared__ double As[64 * 16];    // 8 KB
  __shared__ double Bs[128 * 16];   // 16 KB
  const int f = *dflag;
  const int tid  = threadIdx.x;
  const int lane = tid & 63;
  const int wave = tid >> 6;                  // 0..3
  const int wr = wave >> 1, wc = wave & 1;    // rows: wr*32, cols: wc*64
  const int lm = lane & 15, lq = lane >> 4;
  const int m0 = blockIdx.y * 64, n0 = blockIdx.x * 128;
  const int axor = (lm & 7) << 1;             // read-side k-xor (row&7 == lm&7)

  vd4 acc[2][4];
#pragma unroll
  for (int i = 0; i < 2; ++i)
#pragma unroll
    for (int j = 0; j < 4; ++j)
#pragma unroll
      for (int r = 0; r < 4; ++r) acc[i][j][r] = 0.0;

  for (int k0 = 0; k0 < INTER; k0 += 16) {
    // A: 512 chunks of 16B (2/thread); B: 1024 chunks (4/thread).
    // chunk c -> LDS bytes 16c; logical m = c>>3, kswz = (c&7)*2,
    // global k = kswz ^ (2*(m&7)).
#pragma unroll
    for (int i = 0; i < 2; ++i) {
      const int c  = i * 256 + tid;
      const int m  = c >> 3;
      const int kk = ((c & 7) << 1) ^ ((m & 7) << 1);
      gld_lds16(A + (size_t)(m0 + m) * INTER + (k0 + kk), (char*)As + c * 16);
    }
#pragma unroll
    for (int i = 0; i < 4; ++i) {
      const int c  = i * 256 + tid;
      const int m  = c >> 3;
      const int kk = ((c & 7) << 1) ^ ((m & 7) << 1);
      gld_lds16(B + (size_t)(n0 + m) * INTER + (k0 + kk), (char*)Bs + c * 16);
    }
    __syncthreads();   // compiler drains vmcnt before s_barrier

#pragma unroll
    for (int ks = 0; ks < 4; ++ks) {
      const int kx = (ks * 4 + lq) ^ axor;
      double a[2], b[4];
      a[0] = As[(wr * 32 + lm) * 16 + kx];
      a[1] = As[(wr * 32 + 16 + lm) * 16 + kx];
#pragma unroll
      for (int j = 0; j < 4; ++j)
        b[j] = Bs[(wc * 64 + j * 16 + lm) * 16 + kx];
#pragma unroll
      for (int i = 0; i < 2; ++i)
#pragma unroll
        for (int j = 0; j < 4; ++j)
          acc[i][j] = __builtin_amdgcn_mfma_f64_16x16x4f64(a[i], b[j], acc[i][j], 0, 0, 0);
    }
    __syncthreads();
  }

  // epilogue: D col = lane&15, row = (lane>>4)*4 + reg
#pragma unroll
  for (int j = 0; j < 4; ++j) {
    const int col = n0 + wc * 64 + j * 16 + lm;
    const double bv = f ? (double)bf2f(((const unsigned short*)biasv)[col])
                        : (double)((const float*)biasv)[col];
#pragma unroll
    for (int i = 0; i < 2; ++i) {
      const int row = m0 + wr * 32 + i * 16 + lq * 4;
#pragma unroll
      for (int r = 0; r < 4; ++r)
        C[(size_t)(row + r) * CODE + col] = fmax(acc[i][j][r] + bv, 0.0);
    }
  }
}

// ---------------------------------------------------------------------------
// FP64 MFMA GEMM NT (layer 1): C = relu(A[arow0+m,:]·B[n,:] + bias[n]) f64.
// 64x64 tile, 4 waves. A/B converted inline (x is f32/bf16).
// ---------------------------------------------------------------------------
template<bool A_IS_F64>
__global__ __launch_bounds__(256) void gemm_nt_f64_mfma(
    const void* __restrict__ Av, const void* __restrict__ Bv,
    const void* __restrict__ biasv, double* __restrict__ C,
    int N, int K, int arow0, const int* __restrict__ dflag)
{
  __shared__ double As[16][64];   // [k][m]
  __shared__ double Bs[16][64];   // [k][n]
  const int f = *dflag;
  const int tid  = threadIdx.x;
  const int lane = tid & 63;
  const int wave = tid >> 6;            // 0..3
  const int wr = wave >> 1, wc = wave & 1;
  const int m0 = blockIdx.y * 64, n0 = blockIdx.x * 64;

  const int srow = tid >> 2;            // 0..63 staging row
  const int sk4  = (tid & 3) << 2;      // 0,4,8,12

  vd4 acc[2][2];
#pragma unroll
  for (int i = 0; i < 2; ++i)
#pragma unroll
    for (int j = 0; j < 2; ++j)
#pragma unroll
      for (int r = 0; r < 4; ++r) acc[i][j][r] = 0.0;

  const int lm = lane & 15;             // m/n within 16-tile
  const int lq = lane >> 4;             // k within 4-chunk

  for (int k0 = 0; k0 < K; k0 += 16) {
    // ---- stage A tile (64 rows x 16 k) ----
    if (A_IS_F64) {
      const double* Ap = (const double*)Av + (size_t)(arow0 + m0 + srow) * K + (k0 + sk4);
      As[sk4 + 0][srow] = Ap[0]; As[sk4 + 1][srow] = Ap[1];
      As[sk4 + 2][srow] = Ap[2]; As[sk4 + 3][srow] = Ap[3];
    } else if (f) {
      ushort4 t = *(const ushort4*)((const unsigned short*)Av +
                   (size_t)(arow0 + m0 + srow) * K + (k0 + sk4));
      As[sk4 + 0][srow] = (double)bf2f(t.x); As[sk4 + 1][srow] = (double)bf2f(t.y);
      As[sk4 + 2][srow] = (double)bf2f(t.z); As[sk4 + 3][srow] = (double)bf2f(t.w);
    } else {
      float4 t = *(const float4*)((const float*)Av +
                  (size_t)(arow0 + m0 + srow) * K + (k0 + sk4));
      As[sk4 + 0][srow] = (double)t.x; As[sk4 + 1][srow] = (double)t.y;
      As[sk4 + 2][srow] = (double)t.z; As[sk4 + 3][srow] = (double)t.w;
    }
    // ---- stage B tile (64 rows x 16 k) ----
    if (f) {
      ushort4 t = *(const ushort4*)((const unsigned short*)Bv +
                   (size_t)(n0 + srow) * K + (k0 + sk4));
      Bs[sk4 + 0][srow] = (double)bf2f(t.x); Bs[sk4 + 1][srow] = (double)bf2f(t.y);
      Bs[sk4 + 2][srow] = (double)bf2f(t.z); Bs[sk4 + 3][srow] = (double)bf2f(t.w);
    } else {
      float4 t = *(const float4*)((const float*)Bv +
                  (size_t)(n0 + srow) * K + (k0 + sk4));
      Bs[sk4 + 0][srow] = (double)t.x; Bs[sk4 + 1][srow] = (double)t.y;
      Bs[sk4 + 2][srow] = (double)t.z; Bs[sk4 + 3][srow] = (double)t.w;
    }
    __syncthreads();

#pragma unroll
    for (int ks = 0; ks < 4; ++ks) {
      const int kk = ks * 4 + lq;
      double a0 = As[kk][wr * 32 + lm];
      double a1 = As[kk][wr * 32 + 16 + lm];
      double b0 = Bs[kk][wc * 32 + lm];
      double b1 = Bs[kk][wc * 32 + 16 + lm];
      acc[0][0] = __builtin_amdgcn_mfma_f64_16x16x4f64(a0, b0, acc[0][0], 0, 0, 0);
      acc[0][1] = __builtin_amdgcn_mfma_f64_16x16x4f64(a0, b1, acc[0][1], 0, 0, 0);
      acc[1][0] = __builtin_amdgcn_mfma_f64_16x16x4f64(a1, b0, acc[1][0], 0, 0, 0);
      acc[1][1] = __builtin_amdgcn_mfma_f64_16x16x4f64(a1, b1, acc[1][1], 0, 0, 0);
    }
    __syncthreads();
  }

  // ---- epilogue: D col = lane&15, row = (lane>>4)*4 + reg ----
#pragma unroll
  for (int tc = 0; tc < 2; ++tc) {
    const int col = n0 + wc * 32 + tc * 16 + lm;
    const double bv = f ? (double)bf2f(((const unsigned short*)biasv)[col])
                        : (double)((const float*)biasv)[col];
#pragma unroll
    for (int tr = 0; tr < 2; ++tr) {
#pragma unroll
      for (int r = 0; r < 4; ++r) {
        const int row = m0 + wr * 32 + tr * 16 + lq * 4 + r;
        C[(size_t)row * N + col] = fmax(acc[tr][tc][r] + bv, 0.0);
      }
    }
  }
}

// ---------------------------------------------------------------------------
// One-time: split W4 [784][1024] (f32 or bf16) into bf16 hi|lo pairs,
// padded to 896 rows (pad rows zeroed).  B2 layout: [896][2048] ushort,
// cols 0..1023 = hi(W4[n][k]), cols 1024..2047 = lo(W4[n][k]).
// ---------------------------------------------------------------------------
__global__ __launch_bounds__(256) void convert_w4(
    const void* __restrict__ W4v, unsigned short* __restrict__ B2,
    const int* __restrict__ dflag)
{
  const int f = *dflag;
  const int n = blockIdx.x;            // 0..895
  const int t = threadIdx.x;           // 4 elems each
  ushort4 hi, lo;
  hi.x = hi.y = hi.z = hi.w = 0;
  lo.x = lo.y = lo.z = lo.w = 0;
  if (n < IN_DIM) {
    float v0, v1, v2, v3;
    if (f) {
      ushort4 r = *(const ushort4*)((const unsigned short*)W4v + (size_t)n * INTER + 4 * t);
      v0 = bf2f(r.x); v1 = bf2f(r.y); v2 = bf2f(r.z); v3 = bf2f(r.w);
    } else {
      float4 r = *(const float4*)((const float*)W4v + (size_t)n * INTER + 4 * t);
      v0 = r.x; v1 = r.y; v2 = r.z; v3 = r.w;
    }
    hi.x = f2bf_rn(v0); lo.x = f2bf_rn(v0 - bf2f(hi.x));
    hi.y = f2bf_rn(v1); lo.y = f2bf_rn(v1 - bf2f(hi.y));
    hi.z = f2bf_rn(v2); lo.z = f2bf_rn(v2 - bf2f(hi.z));
    hi.w = f2bf_rn(v3); lo.w = f2bf_rn(v3 - bf2f(hi.w));
  }
  *(ushort4*)(B2 + (size_t)n * 2048 + 4 * t) = hi;
  *(ushort4*)(B2 + (size_t)n * 2048 + 1024 + 4 * t) = lo;
}

// ---------------------------------------------------------------------------
// Layer-4 GEMM via bf16 MFMA with hi/lo split-K emulation (~f32 accuracy).
// 128x128 tile, BK=32, 4 waves, 16x16x32 MFMA, global_load_lds staging.
// ---------------------------------------------------------------------------
__global__ __launch_bounds__(256) void gemm_l4_bf16(
    const unsigned short* __restrict__ A2,   // [CH][2048] hi|lo
    const unsigned short* __restrict__ B2,   // [896][2048] hi|lo (pad zeroed)
    const void* __restrict__ biasv, float* __restrict__ Cout,
    int crow0, const int* __restrict__ dflag)
{
  __shared__ unsigned short As[128 * 32];    // 8 KB, rows of 32 bf16 (64 B)
  __shared__ unsigned short Bs[128 * 32];    // 8 KB
  const int f = *dflag;
  const int tid  = threadIdx.x;
  const int lane = tid & 63;
  const int wave = tid >> 6;                 // 0..3
  const int wr = wave >> 1, wc = wave & 1;   // 2x2 wave grid of 64x64
  const int lm = lane & 15, lg = lane >> 4;
  const int m0 = blockIdx.y * 128, n0 = blockIdx.x * 128;

  f32x4 acc[4][4];
#pragma unroll
  for (int i = 0; i < 4; ++i)
#pragma unroll
    for (int j = 0; j < 4; ++j)
#pragma unroll
      for (int r = 0; r < 4; ++r) acc[i][j][r] = 0.0f;

  const char* a2b = (const char*)A2;
  const char* b2b = (const char*)B2;

  for (int kt = 0; kt < 96; ++kt) {
    const int s   = kt >> 5;                 // segment 0,1,2
    const int kin = (kt & 31) << 5;          // 0..992
    const int ka  = ((s == 1) ? 1024 : 0) + kin;   // A half: lo only in seg 1
    const int kb  = ((s == 2) ? 1024 : 0) + kin;   // B half: lo only in seg 2
#pragma unroll
    for (int i = 0; i < 2; ++i) {
      const int c   = i * 256 + tid;         // chunk id
      const int row = c >> 2;                // 0..127
      const int cb  = (c & 3) * 16;          // byte within 64B row
      gld_lds16(a2b + ((size_t)(m0 + row) * 4096 + (size_t)(ka * 2 + cb)),
                (char*)As + c * 16);
      gld_lds16(b2b + ((size_t)(n0 + row) * 4096 + (size_t)(kb * 2 + cb)),
                (char*)Bs + c * 16);
    }
    __syncthreads();                         // drains vmcnt before barrier

    short8 a[4], b[4];
#pragma unroll
    for (int i = 0; i < 4; ++i) {
      a[i] = *(const short8*)((const char*)As + (wr * 64 + i * 16 + lm) * 64 + lg * 16);
      b[i] = *(const short8*)((const char*)Bs + (wc * 64 + i * 16 + lm) * 64 + lg * 16);
    }
#pragma unroll
    for (int i = 0; i < 4; ++i)
#pragma unroll
      for (int j = 0; j < 4; ++j)
        acc[i][j] = __builtin_amdgcn_mfma_f32_16x16x32_bf16(a[i], b[j], acc[i][j], 0, 0, 0);
    __syncthreads();
  }

  // ---- epilogue: D col = lane&15, row = (lane>>4)*4 + reg ----
#pragma unroll
  for (int j = 0; j < 4; ++j) {
    const int col = n0 + wc * 64 + j * 16 + lm;
    if (col < IN_DIM) {
      const float bv = f ? bf2f(((const unsigned short*)biasv)[col])
                         : ((const float*)biasv)[col];
#pragma unroll
      for (int i = 0; i < 4; ++i) {
        const int row0 = crow0 + m0 + wr * 64 + i * 16 + lg * 4;
#pragma unroll
        for (int r = 0; r < 4; ++r)
          Cout[(size_t)(row0 + r) * IN_DIM + col] = fmaxf(acc[i][j][r] + bv, 0.0f);
      }
    }
  }
}

// ---------------------------------------------------------------------------
// Transpose W3 [1024][2048] -> W3T fp32 [2048][1024] for coalesced gather.
// ---------------------------------------------------------------------------
__global__ __launch_bounds__(256) void transpose_w3(
    const void* __restrict__ W3v, float* __restrict__ W3T, const int* __restrict__ dflag)
{
  __shared__ float tile[32][33];
  const int f = *dflag;
  const int tx = threadIdx.x & 31, ty = threadIdx.x >> 5;  // 32 x 8
  const int c0 = blockIdx.x * 32;
  const int r0 = blockIdx.y * 32;
#pragma unroll
  for (int i = 0; i < 32; i += 8) {
    size_t off = (size_t)(r0 + ty + i) * CODE + (c0 + tx);
    tile[ty + i][tx] = f ? bf2f(((const unsigned short*)W3v)[off])
                         : ((const float*)W3v)[off];
  }
  __syncthreads();
#pragma unroll
  for (int i = 0; i < 32; i += 8)
    W3T[(size_t)(c0 + ty + i) * INTER + (r0 + tx)] = tile[tx][ty + i];
}

// ---------------------------------------------------------------------------
// Block scans (256 threads).
// ---------------------------------------------------------------------------
__device__ __forceinline__ unsigned scan256_incl(unsigned x, unsigned* buf, int tid) {
  __syncthreads();
  buf[tid] = x; __syncthreads();
  for (int off = 1; off < 256; off <<= 1) {
    unsigned add = (tid >= off) ? buf[tid - off] : 0u;
    __syncthreads();
    x += add; buf[tid] = x;
    __syncthreads();
  }
  return x;
}
__device__ __forceinline__ unsigned scan256_suffix(unsigned x, unsigned* buf, int tid) {
  __syncthreads();
  buf[tid] = x; __syncthreads();
  for (int off = 1; off < 256; off <<= 1) {
    unsigned add = (tid + off < 256) ? buf[tid + off] : 0u;
    __syncthreads();
    x += add; buf[tid] = x;
    __syncthreads();
  }
  return x;
}

// ---------------------------------------------------------------------------
// FP64 per-row top-64 radix select (44-bit key, ties lowest-index-first),
// fp64 stripe means, top-4 stripes, compaction to (f32 val, idx, nnz).
// ---------------------------------------------------------------------------
__global__ __launch_bounds__(256) void topk_compact_f64(
    const double* __restrict__ C, float* __restrict__ ovals,
    int* __restrict__ oidxs, int* __restrict__ onnz)
{
  __shared__ double v[CODE];            // 16 KB
  __shared__ unsigned hist[CODE];       // 8 KB
  __shared__ unsigned sbuf[256];
  __shared__ unsigned sres0, sres1, sres3;
  __shared__ int sres2;
  __shared__ double savg[NSTRIPE];
  const int tid = threadIdx.x;
  const int row = blockIdx.x;

  const double2* c2 = (const double2*)(C + (size_t)row * CODE);
#pragma unroll
  for (int i = 0; i < 4; ++i)
    ((double2*)v)[tid + 256 * i] = c2[tid + 256 * i];
  __syncthreads();

  ull u[8];
#pragma unroll
  for (int i = 0; i < 8; ++i) u[i] = __double_as_longlong(v[tid * 8 + i]);

  const int shifts[4] = {52, 41, 30, 19};
  unsigned kr = KNEUR;
  ull prefix = 0ull, pmask = 0ull;
  bool tz = false;

  for (int p = 0; p < 4; ++p) {
    const int sh = shifts[p];
    for (int i = tid; i < CODE; i += 256) hist[i] = 0u;
    __syncthreads();
#pragma unroll
    for (int i = 0; i < 8; ++i)
      if (u[i] != 0ull && (u[i] & pmask) == prefix)
        atomicAdd(&hist[(unsigned)((u[i] >> sh) & 2047ull)], 1u);
    __syncthreads();
    unsigned csum = 0u;
#pragma unroll
    for (int j = 0; j < 8; ++j) csum += hist[tid * 8 + j];
    unsigned sc = scan256_suffix(csum, sbuf, tid);
    unsigned scn = (tid < 255) ? sbuf[tid + 1] : 0u;
    if (p == 0 && tid == 0) sres2 = (sc < kr) ? 1 : 0;
    if (sc >= kr && scn < kr) {
      unsigned cum = scn;
      for (int b = 7; b >= 0; --b) {
        unsigned hb = hist[tid * 8 + b];
        if (cum + hb >= kr) { sres0 = (unsigned)(tid * 8 + b); sres1 = cum; break; }
        cum += hb;
      }
    }
    __syncthreads();
    if (p == 0 && sres2) { tz = true; break; }
    kr -= sres1;
    prefix |= ((ull)sres0) << sh;
    pmask  |= 2047ull << sh;
    __syncthreads();
  }

  const ull tkey = tz ? 0ull : (prefix >> 19);

  unsigned gt = 0u, eq = 0u;
#pragma unroll
  for (int i = 0; i < 8; ++i) {
    ull k = u[i] >> 19;
    gt += (k > tkey) ? 1u : 0u;
    eq += (k == tkey) ? 1u : 0u;
  }
  unsigned eqincl = scan256_incl(eq, sbuf, tid);
  unsigned eqbase = eqincl - eq;
  (void)scan256_incl(gt, sbuf, tid);
  unsigned total_gt = sbuf[255];
  unsigned need_eq = KNEUR - total_gt;
  unsigned er = eqbase;
#pragma unroll
  for (int i = 0; i < 8; ++i) {
    ull k = u[i] >> 19;
    bool sel = (k > tkey);
    if (k == tkey) { sel = (er < need_eq); ++er; }
    if (!sel) v[tid * 8 + i] = 0.0;
  }
  __syncthreads();

  if (tid < NSTRIPE) {
    const double* sv = v + tid * SDIM;
    double r0 = sv[0], r1 = sv[1], r2 = sv[2], r3 = sv[3],
           r4 = sv[4], r5 = sv[5], r6 = sv[6], r7 = sv[7];
    for (int i = 8; i < SDIM; i += 8) {
      r0 += sv[i + 0]; r1 += sv[i + 1]; r2 += sv[i + 2]; r3 += sv[i + 3];
      r4 += sv[i + 4]; r5 += sv[i + 5]; r6 += sv[i + 6]; r7 += sv[i + 7];
    }
    savg[tid] = (((r0 + r1) + (r2 + r3)) + ((r4 + r5) + (r6 + r7))) * 0.015625;
  }
  __syncthreads();
  if (tid == 0) {
    unsigned sm = 0u;
    for (int it = 0; it < KSTR; ++it) {
      double best = -1.0; int bi = 0;
      for (int s = 0; s < NSTRIPE; ++s)
        if (!((sm >> s) & 1u) && savg[s] > best) { best = savg[s]; bi = s; }
      sm |= (1u << bi);
    }
    sres3 = sm;
  }
  __syncthreads();
  const unsigned sm = sres3;

  const bool son = ((sm >> (tid >> 3)) & 1u) != 0u;
  double mv[8];
  unsigned act = 0u, cnt = 0u;
#pragma unroll
  for (int i = 0; i < 8; ++i) {
    mv[i] = v[tid * 8 + i];
    bool a = son && (mv[i] != 0.0);
    act |= (a ? 1u : 0u) << i;
    cnt += a ? 1u : 0u;
  }
  unsigned cincl = scan256_incl(cnt, sbuf, tid);
  unsigned pos = cincl - cnt;
  float* vrow = ovals + (size_t)row * KNEUR;
  int* irow = oidxs + (size_t)row * KNEUR;
#pragma unroll
  for (int i = 0; i < 8; ++i) {
    if ((act >> i) & 1u) {
      vrow[pos] = (float)mv[i];
      irow[pos] = tid * 8 + i;
      ++pos;
    }
  }
  if (tid == 255) onnz[row] = (int)cincl;
}

// ---------------------------------------------------------------------------
// Sparse decode (fp32): d[row,:] = relu(b3 + sum_j val_j * W3T[idx_j,:]).
// Epilogue writes d as bf16 hi|lo pairs (A2 [CH][2048]) for layer 4.
// ---------------------------------------------------------------------------
__global__ __launch_bounds__(256) void sparse_decode(
    const float* __restrict__ W3T, const void* __restrict__ b3v,
    const float* __restrict__ vals, const int* __restrict__ idxs,
    const int* __restrict__ nnz, unsigned short* __restrict__ A2,
    const int* __restrict__ dflag)
{
  __shared__ float sv[KNEUR];
  __shared__ int si[KNEUR];
  __shared__ int scnt;
  const int f = *dflag;
  const int tid = threadIdx.x;
  const int row = blockIdx.x;
  if (tid == 0) scnt = nnz[row];
  if (tid < KNEUR) {
    sv[tid] = vals[(size_t)row * KNEUR + tid];
    si[tid] = idxs[(size_t)row * KNEUR + tid];
  }
  __syncthreads();
  const int cnt = scnt;
  float4 acc;
  if (f) {
    const unsigned short* b3b = (const unsigned short*)b3v;
    acc.x = bf2f(b3b[4 * tid + 0]); acc.y = bf2f(b3b[4 * tid + 1]);
    acc.z = bf2f(b3b[4 * tid + 2]); acc.w = bf2f(b3b[4 * tid + 3]);
  } else {
    acc = ((const float4*)b3v)[tid];
  }
  for (int j = 0; j < cnt; ++j) {
    const float vv = sv[j];
    const float4 w = ((const float4*)(W3T + (size_t)si[j] * INTER))[tid];
    acc.x = fmaf(vv, w.x, acc.x);
    acc.y = fmaf(vv, w.y, acc.y);
    acc.z = fmaf(vv, w.z, acc.z);
    acc.w = fmaf(vv, w.w, acc.w);
  }
  acc.x = fmaxf(acc.x, 0.f); acc.y = fmaxf(acc.y, 0.f);
  acc.z = fmaxf(acc.z, 0.f); acc.w = fmaxf(acc.w, 0.f);

  ushort4 hi, lo;
  hi.x = f2bf_rn(acc.x); lo.x = f2bf_rn(acc.x - bf2f(hi.x));
  hi.y = f2bf_rn(acc.y); lo.y = f2bf_rn(acc.y - bf2f(hi.y));
  hi.z = f2bf_rn(acc.z); lo.z = f2bf_rn(acc.z - bf2f(hi.z));
  hi.w = f2bf_rn(acc.w); lo.w = f2bf_rn(acc.w - bf2f(hi.w));
  *(ushort4*)(A2 + (size_t)row * 2048 + 4 * tid) = hi;
  *(ushort4*)(A2 + (size_t)row * 2048 + 1024 + 4 * tid) = lo;
}

// ---------------------------------------------------------------------------
extern "C" void kernel_launch(void* const* d_in, const int* in_sizes, int n_in,
                              void* d_out, int out_size, void* d_ws, size_t ws_size,
                              hipStream_t stream)
{
  const void* x  = d_in[0];
  const void* W1 = d_in[1];
  const void* b1 = d_in[2];
  const void* W2 = d_in[3];
  const void* b2 = d_in[4];
  const void* W3 = d_in[5];
  const void* b3 = d_in[6];
  const void* W4 = d_in[7];
  const void* b4 = d_in[8];

  // layout: [flag 256B][W3T 8MB][B2 896*2048*2][W2d 16MB]
  //         [h64 CH*8K (A2 overlays)][c64 CH*16K][cv][ci][cn]
  const size_t W3T_BYTES = (size_t)CODE * INTER * 4;
  const size_t B2_BYTES  = (size_t)NPAD * 2048 * 2;
  const size_t W2D_BYTES = (size_t)CODE * INTER * 8;
  int CH = BATCH;
  while (CH > 128) {
    size_t need = 256 + W3T_BYTES + B2_BYTES + W2D_BYTES +
                  (size_t)CH * (8192 + 16384 + 256 + 256 + 4);
    if (need <= ws_size) break;
    CH >>= 1;
  }
  char*   w    = (char*)d_ws;
  int*    flag = (int*)w;
  float*  W3T  = (float*)(w + 256);
  unsigned short* B2w = (unsigned short*)(w + 256 + W3T_BYTES);
  double* W2d  = (double*)(w + 256 + W3T_BYTES + B2_BYTES);
  char*   p    = w + 256 + W3T_BYTES + B2_BYTES + W2D_BYTES;
  double* h64  = (double*)p;                                 // CH*1024 f64
  unsigned short* A2 = (unsigned short*)p;                   // overlays h64 (dead by then)
  double* c64  = (double*)(p + (size_t)CH * 8192);           // CH*2048 f64
  float*  cv   = (float*)(p + (size_t)CH * 24576);           // CH*64 f32
  int*    ci   = (int*)  (p + (size_t)CH * 24576 + (size_t)CH * 256);
  int*    cn   = (int*)  (p + (size_t)CH * 24576 + (size_t)CH * 512);

  detect_dtype<<<1, 256, 0, stream>>>((const unsigned*)W1, flag);
  transpose_w3<<<dim3(CODE / 32, INTER / 32), 256, 0, stream>>>(W3, W3T, flag);
  convert_w4<<<NPAD, 256, 0, stream>>>(W4, B2w, flag);
  convert_w2_f64<<<CODE, 256, 0, stream>>>(W2, W2d, flag);

  for (int r0 = 0; r0 < BATCH; r0 += CH) {
    // h = relu(x @ W1^T + b1) in f64   [CH, 1024], K=784  (MFMA f64, 64-tile)
    gemm_nt_f64_mfma<false><<<dim3(INTER / 64, CH / 64), 256, 0, stream>>>(
        x, W1, b1, h64, INTER, IN_DIM, r0, flag);

    // c = relu(h @ W2^T + b2) in f64   [CH, 2048], K=1024  (v2: 64x128 DMA MFMA)
    gemm2_f64_v2<<<dim3(CODE / 128, CH / 64), 256, 0, stream>>>(
        h64, W2d, b2, c64, flag);

    // exact top-64 + stripe top-4 on f64 values -> compact sparse code
    topk_compact_f64<<<CH, 256, 0, stream>>>(c64, cv, ci, cn);

    // d = relu(c_sparse @ W3^T + b3) -> bf16 hi|lo split (overlays h64)
    sparse_decode<<<CH, 256, 0, stream>>>(W3T, b3, cv, ci, cn, A2, flag);

    // out[r0:r0+CH] = relu(d @ W4^T + b4) via bf16 split-K MFMA, f32 out
    gemm_l4_bf16<<<dim3(NPAD / 128, CH / 128), 256, 0, stream>>>(
        A2, B2w, b4, (float*)d_out, r0, flag);
  }
}

// Round 13
// 2073.050 us; speedup vs baseline: 1.2981x; 1.0317x over previous
//
#include <hip/hip_runtime.h>
#include <hip/hip_bf16.h>
#include <stdint.h>

typedef unsigned long long ull;
typedef double vd4 __attribute__((ext_vector_type(4)));
typedef __attribute__((ext_vector_type(8))) short short8;
typedef __attribute__((ext_vector_type(4))) float f32x4;

#define BATCH   16384
#define IN_DIM  784
#define INTER   1024
#define CODE    2048
#define NSTRIPE 32
#define SDIM    64
#define KNEUR   64
#define KSTR    4
#define NPAD    896   // 784 padded to 7*128 for the layer-4 MFMA tile grid

__device__ __forceinline__ float bf2f(unsigned short u) {
  return __uint_as_float(((unsigned)u) << 16);
}

// round-to-nearest-even f32 -> bf16 bits
__device__ __forceinline__ unsigned short f2bf_rn(float x) {
  unsigned u = __float_as_uint(x);
  u += 0x7FFFu + ((u >> 16) & 1u);
  return (unsigned short)(u >> 16);
}

// async global->LDS, 16B per lane (dest must be linear in lane order)
__device__ __forceinline__ void gld_lds16(const void* g, void* l) {
  __builtin_amdgcn_global_load_lds(
      (__attribute__((address_space(1))) void*)(g),
      (__attribute__((address_space(3))) void*)(l), 16, 0, 0);
}

// ---------------------------------------------------------------------------
// Input dtype detector (insurance): flag=1 => inputs are bf16.
// ---------------------------------------------------------------------------
__global__ void detect_dtype(const unsigned* __restrict__ w1raw, int* __restrict__ flag) {
  __shared__ unsigned cnt;
  if (threadIdx.x == 0) cnt = 0u;
  __syncthreads();
  unsigned c = 0;
  for (int i = threadIdx.x; i < 512; i += 256) {
    unsigned e = (w1raw[i] >> 7) & 0xFFu;
    if (e >= 100u && e <= 126u) ++c;
  }
  atomicAdd(&cnt, c);
  __syncthreads();
  if (threadIdx.x == 0) *flag = (cnt > 256u) ? 1 : 0;
}

// ---------------------------------------------------------------------------
// One-time: W2 [2048][1024] (f32 or bf16) -> f64.
// ---------------------------------------------------------------------------
__global__ __launch_bounds__(256) void convert_w2_f64(
    const void* __restrict__ W2v, double* __restrict__ W2d,
    const int* __restrict__ dflag)
{
  const int f = *dflag;
  const size_t base = (size_t)blockIdx.x * INTER + 4u * threadIdx.x;
  double v0, v1, v2, v3;
  if (f) {
    ushort4 r = *(const ushort4*)((const unsigned short*)W2v + base);
    v0 = (double)bf2f(r.x); v1 = (double)bf2f(r.y);
    v2 = (double)bf2f(r.z); v3 = (double)bf2f(r.w);
  } else {
    float4 r = *(const float4*)((const float*)W2v + base);
    v0 = r.x; v1 = r.y; v2 = r.z; v3 = r.w;
  }
  W2d[base + 0] = v0; W2d[base + 1] = v1;
  W2d[base + 2] = v2; W2d[base + 3] = v3;
}

// ---------------------------------------------------------------------------
// Layer-2 FP64 MFMA GEMM v2 (verified r10: 571us, MfmaUtil 82.6%, occ 41%).
// BM=64, BN=128, BK=16, 256 thr / 4 waves, wave tile 32x64 (acc 64 regs).
// global_load_lds staging, XOR-swizzled source+read. Bitwise-exact C.
// ---------------------------------------------------------------------------
__global__ __launch_bounds__(256, 3) void gemm2_f64_v2(
    const double* __restrict__ A, const double* __restrict__ B,
    const void* __restrict__ biasv, double* __restrict__ C,
    const int* __restrict__ dflag)
{
  __shared__ double As[64 * 16];    // 8 KB
  __shared__ double Bs[128 * 16];   // 16 KB
  const int f = *dflag;
  const int tid  = threadIdx.x;
  const int lane = tid & 63;
  const int wave = tid >> 6;                  // 0..3
  const int wr = wave >> 1, wc = wave & 1;    // rows: wr*32, cols: wc*64
  const int lm = lane & 15, lq = lane >> 4;
  const int m0 = blockIdx.y * 64, n0 = blockIdx.x * 128;
  const int axor = (lm & 7) << 1;             // read-side k-xor (row&7 == lm&7)

  vd4 acc[2][4];
#pragma unroll
  for (int i = 0; i < 2; ++i)
#pragma unroll
    for (int j = 0; j < 4; ++j)
#pragma unroll
      for (int r = 0; r < 4; ++r) acc[i][j][r] = 0.0;

  for (int k0 = 0; k0 < INTER; k0 += 16) {
#pragma unroll
    for (int i = 0; i < 2; ++i) {
      const int c  = i * 256 + tid;
      const int m  = c >> 3;
      const int kk = ((c & 7) << 1) ^ ((m & 7) << 1);
      gld_lds16(A + (size_t)(m0 + m) * INTER + (k0 + kk), (char*)As + c * 16);
    }
#pragma unroll
    for (int i = 0; i < 4; ++i) {
      const int c  = i * 256 + tid;
      const int m  = c >> 3;
      const int kk = ((c & 7) << 1) ^ ((m & 7) << 1);
      gld_lds16(B + (size_t)(n0 + m) * INTER + (k0 + kk), (char*)Bs + c * 16);
    }
    __syncthreads();   // compiler drains vmcnt before s_barrier

#pragma unroll
    for (int ks = 0; ks < 4; ++ks) {
      const int kx = (ks * 4 + lq) ^ axor;
      double a[2], b[4];
      a[0] = As[(wr * 32 + lm) * 16 + kx];
      a[1] = As[(wr * 32 + 16 + lm) * 16 + kx];
#pragma unroll
      for (int j = 0; j < 4; ++j)
        b[j] = Bs[(wc * 64 + j * 16 + lm) * 16 + kx];
#pragma unroll
      for (int i = 0; i < 2; ++i)
#pragma unroll
        for (int j = 0; j < 4; ++j)
          acc[i][j] = __builtin_amdgcn_mfma_f64_16x16x4f64(a[i], b[j], acc[i][j], 0, 0, 0);
    }
    __syncthreads();
  }

  // epilogue: D col = lane&15, row = (lane>>4)*4 + reg
#pragma unroll
  for (int j = 0; j < 4; ++j) {
    const int col = n0 + wc * 64 + j * 16 + lm;
    const double bv = f ? (double)bf2f(((const unsigned short*)biasv)[col])
                        : (double)((const float*)biasv)[col];
#pragma unroll
    for (int i = 0; i < 2; ++i) {
      const int row = m0 + wr * 32 + i * 16 + lq * 4;
#pragma unroll
      for (int r = 0; r < 4; ++r)
        C[(size_t)(row + r) * CODE + col] = fmax(acc[i][j][r] + bv, 0.0);
    }
  }
}

// ---------------------------------------------------------------------------
// FP64 MFMA GEMM NT (layer 1): C = relu(A[arow0+m,:]·B[n,:] + bias[n]) f64.
// 64x64 tile, 4 waves. A/B converted inline (x is f32/bf16).
// r11: LDS padded [16][65] — [16][64] put a 4-way same-bank collision on
// every staging write AND fragment read (row stride 64*8B == 0 mod banks);
// +1 pad makes writes exactly 2-way (free) and reads ~2-way. Bitwise-exact.
// ---------------------------------------------------------------------------
template<bool A_IS_F64>
__global__ __launch_bounds__(256) void gemm_nt_f64_mfma(
    const void* __restrict__ Av, const void* __restrict__ Bv,
    const void* __restrict__ biasv, double* __restrict__ C,
    int N, int K, int arow0, const int* __restrict__ dflag)
{
  __shared__ double As[16][65];   // [k][m], +1 pad
  __shared__ double Bs[16][65];   // [k][n], +1 pad
  const int f = *dflag;
  const int tid  = threadIdx.x;
  const int lane = tid & 63;
  const int wave = tid >> 6;            // 0..3
  const int wr = wave >> 1, wc = wave & 1;
  const int m0 = blockIdx.y * 64, n0 = blockIdx.x * 64;

  const int srow = tid >> 2;            // 0..63 staging row
  const int sk4  = (tid & 3) << 2;      // 0,4,8,12

  vd4 acc[2][2];
#pragma unroll
  for (int i = 0; i < 2; ++i)
#pragma unroll
    for (int j = 0; j < 2; ++j)
#pragma unroll
      for (int r = 0; r < 4; ++r) acc[i][j][r] = 0.0;

  const int lm = lane & 15;             // m/n within 16-tile
  const int lq = lane >> 4;             // k within 4-chunk

  for (int k0 = 0; k0 < K; k0 += 16) {
    // ---- stage A tile (64 rows x 16 k) ----
    if (A_IS_F64) {
      const double* Ap = (const double*)Av + (size_t)(arow0 + m0 + srow) * K + (k0 + sk4);
      As[sk4 + 0][srow] = Ap[0]; As[sk4 + 1][srow] = Ap[1];
      As[sk4 + 2][srow] = Ap[2]; As[sk4 + 3][srow] = Ap[3];
    } else if (f) {
      ushort4 t = *(const ushort4*)((const unsigned short*)Av +
                   (size_t)(arow0 + m0 + srow) * K + (k0 + sk4));
      As[sk4 + 0][srow] = (double)bf2f(t.x); As[sk4 + 1][srow] = (double)bf2f(t.y);
      As[sk4 + 2][srow] = (double)bf2f(t.z); As[sk4 + 3][srow] = (double)bf2f(t.w);
    } else {
      float4 t = *(const float4*)((const float*)Av +
                  (size_t)(arow0 + m0 + srow) * K + (k0 + sk4));
      As[sk4 + 0][srow] = (double)t.x; As[sk4 + 1][srow] = (double)t.y;
      As[sk4 + 2][srow] = (double)t.z; As[sk4 + 3][srow] = (double)t.w;
    }
    // ---- stage B tile (64 rows x 16 k) ----
    if (f) {
      ushort4 t = *(const ushort4*)((const unsigned short*)Bv +
                   (size_t)(n0 + srow) * K + (k0 + sk4));
      Bs[sk4 + 0][srow] = (double)bf2f(t.x); Bs[sk4 + 1][srow] = (double)bf2f(t.y);
      Bs[sk4 + 2][srow] = (double)bf2f(t.z); Bs[sk4 + 3][srow] = (double)bf2f(t.w);
    } else {
      float4 t = *(const float4*)((const float*)Bv +
                  (size_t)(n0 + srow) * K + (k0 + sk4));
      Bs[sk4 + 0][srow] = (double)t.x; Bs[sk4 + 1][srow] = (double)t.y;
      Bs[sk4 + 2][srow] = (double)t.z; Bs[sk4 + 3][srow] = (double)t.w;
    }
    __syncthreads();

#pragma unroll
    for (int ks = 0; ks < 4; ++ks) {
      const int kk = ks * 4 + lq;
      double a0 = As[kk][wr * 32 + lm];
      double a1 = As[kk][wr * 32 + 16 + lm];
      double b0 = Bs[kk][wc * 32 + lm];
      double b1 = Bs[kk][wc * 32 + 16 + lm];
      acc[0][0] = __builtin_amdgcn_mfma_f64_16x16x4f64(a0, b0, acc[0][0], 0, 0, 0);
      acc[0][1] = __builtin_amdgcn_mfma_f64_16x16x4f64(a0, b1, acc[0][1], 0, 0, 0);
      acc[1][0] = __builtin_amdgcn_mfma_f64_16x16x4f64(a1, b0, acc[1][0], 0, 0, 0);
      acc[1][1] = __builtin_amdgcn_mfma_f64_16x16x4f64(a1, b1, acc[1][1], 0, 0, 0);
    }
    __syncthreads();
  }

  // ---- epilogue: D col = lane&15, row = (lane>>4)*4 + reg ----
#pragma unroll
  for (int tc = 0; tc < 2; ++tc) {
    const int col = n0 + wc * 32 + tc * 16 + lm;
    const double bv = f ? (double)bf2f(((const unsigned short*)biasv)[col])
                        : (double)((const float*)biasv)[col];
#pragma unroll
    for (int tr = 0; tr < 2; ++tr) {
#pragma unroll
      for (int r = 0; r < 4; ++r) {
        const int row = m0 + wr * 32 + tr * 16 + lq * 4 + r;
        C[(size_t)row * N + col] = fmax(acc[tr][tc][r] + bv, 0.0);
      }
    }
  }
}

// ---------------------------------------------------------------------------
// One-time: split W4 [784][1024] (f32 or bf16) into bf16 hi|lo pairs,
// padded to 896 rows (pad rows zeroed).
// ---------------------------------------------------------------------------
__global__ __launch_bounds__(256) void convert_w4(
    const void* __restrict__ W4v, unsigned short* __restrict__ B2,
    const int* __restrict__ dflag)
{
  const int f = *dflag;
  const int n = blockIdx.x;            // 0..895
  const int t = threadIdx.x;           // 4 elems each
  ushort4 hi, lo;
  hi.x = hi.y = hi.z = hi.w = 0;
  lo.x = lo.y = lo.z = lo.w = 0;
  if (n < IN_DIM) {
    float v0, v1, v2, v3;
    if (f) {
      ushort4 r = *(const ushort4*)((const unsigned short*)W4v + (size_t)n * INTER + 4 * t);
      v0 = bf2f(r.x); v1 = bf2f(r.y); v2 = bf2f(r.z); v3 = bf2f(r.w);
    } else {
      float4 r = *(const float4*)((const float*)W4v + (size_t)n * INTER + 4 * t);
      v0 = r.x; v1 = r.y; v2 = r.z; v3 = r.w;
    }
    hi.x = f2bf_rn(v0); lo.x = f2bf_rn(v0 - bf2f(hi.x));
    hi.y = f2bf_rn(v1); lo.y = f2bf_rn(v1 - bf2f(hi.y));
    hi.z = f2bf_rn(v2); lo.z = f2bf_rn(v2 - bf2f(hi.z));
    hi.w = f2bf_rn(v3); lo.w = f2bf_rn(v3 - bf2f(hi.w));
  }
  *(ushort4*)(B2 + (size_t)n * 2048 + 4 * t) = hi;
  *(ushort4*)(B2 + (size_t)n * 2048 + 1024 + 4 * t) = lo;
}

// ---------------------------------------------------------------------------
// Layer-4 GEMM via bf16 MFMA with hi/lo split-K emulation (~f32 accuracy).
// 128x128 tile, BK=32, 4 waves, 16x16x32 MFMA, global_load_lds staging.
// ---------------------------------------------------------------------------
__global__ __launch_bounds__(256) void gemm_l4_bf16(
    const unsigned short* __restrict__ A2,   // [CH][2048] hi|lo
    const unsigned short* __restrict__ B2,   // [896][2048] hi|lo (pad zeroed)
    const void* __restrict__ biasv, float* __restrict__ Cout,
    int crow0, const int* __restrict__ dflag)
{
  __shared__ unsigned short As[128 * 32];    // 8 KB, rows of 32 bf16 (64 B)
  __shared__ unsigned short Bs[128 * 32];    // 8 KB
  const int f = *dflag;
  const int tid  = threadIdx.x;
  const int lane = tid & 63;
  const int wave = tid >> 6;                 // 0..3
  const int wr = wave >> 1, wc = wave & 1;   // 2x2 wave grid of 64x64
  const int lm = lane & 15, lg = lane >> 4;
  const int m0 = blockIdx.y * 128, n0 = blockIdx.x * 128;

  f32x4 acc[4][4];
#pragma unroll
  for (int i = 0; i < 4; ++i)
#pragma unroll
    for (int j = 0; j < 4; ++j)
#pragma unroll
      for (int r = 0; r < 4; ++r) acc[i][j][r] = 0.0f;

  const char* a2b = (const char*)A2;
  const char* b2b = (const char*)B2;

  for (int kt = 0; kt < 96; ++kt) {
    const int s   = kt >> 5;                 // segment 0,1,2
    const int kin = (kt & 31) << 5;          // 0..992
    const int ka  = ((s == 1) ? 1024 : 0) + kin;   // A half: lo only in seg 1
    const int kb  = ((s == 2) ? 1024 : 0) + kin;   // B half: lo only in seg 2
#pragma unroll
    for (int i = 0; i < 2; ++i) {
      const int c   = i * 256 + tid;         // chunk id
      const int row = c >> 2;                // 0..127
      const int cb  = (c & 3) * 16;          // byte within 64B row
      gld_lds16(a2b + ((size_t)(m0 + row) * 4096 + (size_t)(ka * 2 + cb)),
                (char*)As + c * 16);
      gld_lds16(b2b + ((size_t)(n0 + row) * 4096 + (size_t)(kb * 2 + cb)),
                (char*)Bs + c * 16);
    }
    __syncthreads();                         // drains vmcnt before barrier

    short8 a[4], b[4];
#pragma unroll
    for (int i = 0; i < 4; ++i) {
      a[i] = *(const short8*)((const char*)As + (wr * 64 + i * 16 + lm) * 64 + lg * 16);
      b[i] = *(const short8*)((const char*)Bs + (wc * 64 + i * 16 + lm) * 64 + lg * 16);
    }
#pragma unroll
    for (int i = 0; i < 4; ++i)
#pragma unroll
      for (int j = 0; j < 4; ++j)
        acc[i][j] = __builtin_amdgcn_mfma_f32_16x16x32_bf16(a[i], b[j], acc[i][j], 0, 0, 0);
    __syncthreads();
  }

  // ---- epilogue: D col = lane&15, row = (lane>>4)*4 + reg ----
#pragma unroll
  for (int j = 0; j < 4; ++j) {
    const int col = n0 + wc * 64 + j * 16 + lm;
    if (col < IN_DIM) {
      const float bv = f ? bf2f(((const unsigned short*)biasv)[col])
                         : ((const float*)biasv)[col];
#pragma unroll
      for (int i = 0; i < 4; ++i) {
        const int row0 = crow0 + m0 + wr * 64 + i * 16 + lg * 4;
#pragma unroll
        for (int r = 0; r < 4; ++r)
          Cout[(size_t)(row0 + r) * IN_DIM + col] = fmaxf(acc[i][j][r] + bv, 0.0f);
      }
    }
  }
}

// ---------------------------------------------------------------------------
// Transpose W3 [1024][2048] -> W3T fp32 [2048][1024] for coalesced gather.
// ---------------------------------------------------------------------------
__global__ __launch_bounds__(256) void transpose_w3(
    const void* __restrict__ W3v, float* __restrict__ W3T, const int* __restrict__ dflag)
{
  __shared__ float tile[32][33];
  const int f = *dflag;
  const int tx = threadIdx.x & 31, ty = threadIdx.x >> 5;  // 32 x 8
  const int c0 = blockIdx.x * 32;
  const int r0 = blockIdx.y * 32;
#pragma unroll
  for (int i = 0; i < 32; i += 8) {
    size_t off = (size_t)(r0 + ty + i) * CODE + (c0 + tx);
    tile[ty + i][tx] = f ? bf2f(((const unsigned short*)W3v)[off])
                         : ((const float*)W3v)[off];
  }
  __syncthreads();
#pragma unroll
  for (int i = 0; i < 32; i += 8)
    W3T[(size_t)(c0 + ty + i) * INTER + (r0 + tx)] = tile[tx][ty + i];
}

// ---------------------------------------------------------------------------
// Block scans (256 threads) — r11: wave-level shfl scans (4 barriers vs 18,
// no 8-round LDS latency chain). Integer adds: bitwise-identical results.
// Side-effects preserved: buf[tid] holds this thread's scan value on return.
// ---------------------------------------------------------------------------
__device__ __forceinline__ unsigned scan256_incl(unsigned x, unsigned* buf, int tid) {
  const int lane = tid & 63, wave = tid >> 6;
#pragma unroll
  for (int off = 1; off < 64; off <<= 1) {
    unsigned y = __shfl_up(x, off, 64);
    if (lane >= off) x += y;
  }
  __syncthreads();                       // protect buf from previous use
  if (lane == 63) buf[wave] = x;         // wave totals -> buf[0..3]
  __syncthreads();
  unsigned add = 0u;
  if (wave > 0) add += buf[0];
  if (wave > 1) add += buf[1];
  if (wave > 2) add += buf[2];
  x += add;
  __syncthreads();                       // before overwriting buf[0..3]
  buf[tid] = x;
  __syncthreads();
  return x;
}
__device__ __forceinline__ unsigned scan256_suffix(unsigned x, unsigned* buf, int tid) {
  const int lane = tid & 63, wave = tid >> 6;
#pragma unroll
  for (int off = 1; off < 64; off <<= 1) {
    unsigned y = __shfl_down(x, off, 64);
    if (lane + off < 64) x += y;
  }
  __syncthreads();
  if (lane == 0) buf[wave] = x;          // wave totals (suffix) -> buf[0..3]
  __syncthreads();
  unsigned add = 0u;
  if (wave < 3) add += buf[3];
  if (wave < 2) add += buf[2];
  if (wave < 1) add += buf[1];
  x += add;
  __syncthreads();
  buf[tid] = x;
  __syncthreads();
  return x;
}

// ---------------------------------------------------------------------------
// FP64 per-row top-64 radix select (44-bit key, ties lowest-index-first),
// fp64 stripe means, top-4 stripes, compaction to (f32 val, idx, nnz).
// ---------------------------------------------------------------------------
__global__ __launch_bounds__(256) void topk_compact_f64(
    const double* __restrict__ C, float* __restrict__ ovals,
    int* __restrict__ oidxs, int* __restrict__ onnz)
{
  __shared__ double v[CODE];            // 16 KB
  __shared__ unsigned hist[CODE];       // 8 KB
  __shared__ unsigned sbuf[256];
  __shared__ unsigned sres0, sres1, sres3;
  __shared__ int sres2;
  __shared__ double savg[NSTRIPE];
  const int tid = threadIdx.x;
  const int row = blockIdx.x;

  const double2* c2 = (const double2*)(C + (size_t)row * CODE);
#pragma unroll
  for (int i = 0; i < 4; ++i)
    ((double2*)v)[tid + 256 * i] = c2[tid + 256 * i];
  __syncthreads();

  ull u[8];
#pragma unroll
  for (int i = 0; i < 8; ++i) u[i] = __double_as_longlong(v[tid * 8 + i]);

  const int shifts[4] = {52, 41, 30, 19};
  unsigned kr = KNEUR;
  ull prefix = 0ull, pmask = 0ull;
  bool tz = false;

  for (int p = 0; p < 4; ++p) {
    const int sh = shifts[p];
    for (int i = tid; i < CODE; i += 256) hist[i] = 0u;
    __syncthreads();
#pragma unroll
    for (int i = 0; i < 8; ++i)
      if (u[i] != 0ull && (u[i] & pmask) == prefix)
        atomicAdd(&hist[(unsigned)((u[i] >> sh) & 2047ull)], 1u);
    __syncthreads();
    unsigned csum = 0u;
#pragma unroll
    for (int j = 0; j < 8; ++j) csum += hist[tid * 8 + j];
    unsigned sc = scan256_suffix(csum, sbuf, tid);
    unsigned scn = (tid < 255) ? sbuf[tid + 1] : 0u;
    if (p == 0 && tid == 0) sres2 = (sc < kr) ? 1 : 0;
    if (sc >= kr && scn < kr) {
      unsigned cum = scn;
      for (int b = 7; b >= 0; --b) {
        unsigned hb = hist[tid * 8 + b];
        if (cum + hb >= kr) { sres0 = (unsigned)(tid * 8 + b); sres1 = cum; break; }
        cum += hb;
      }
    }
    __syncthreads();
    if (p == 0 && sres2) { tz = true; break; }
    kr -= sres1;
    prefix |= ((ull)sres0) << sh;
    pmask  |= 2047ull << sh;
    __syncthreads();
  }

  const ull tkey = tz ? 0ull : (prefix >> 19);

  unsigned gt = 0u, eq = 0u;
#pragma unroll
  for (int i = 0; i < 8; ++i) {
    ull k = u[i] >> 19;
    gt += (k > tkey) ? 1u : 0u;
    eq += (k == tkey) ? 1u : 0u;
  }
  unsigned eqincl = scan256_incl(eq, sbuf, tid);
  unsigned eqbase = eqincl - eq;
  (void)scan256_incl(gt, sbuf, tid);
  unsigned total_gt = sbuf[255];
  unsigned need_eq = KNEUR - total_gt;
  unsigned er = eqbase;
#pragma unroll
  for (int i = 0; i < 8; ++i) {
    ull k = u[i] >> 19;
    bool sel = (k > tkey);
    if (k == tkey) { sel = (er < need_eq); ++er; }
    if (!sel) v[tid * 8 + i] = 0.0;
  }
  __syncthreads();

  if (tid < NSTRIPE) {
    const double* sv = v + tid * SDIM;
    double r0 = sv[0], r1 = sv[1], r2 = sv[2], r3 = sv[3],
           r4 = sv[4], r5 = sv[5], r6 = sv[6], r7 = sv[7];
    for (int i = 8; i < SDIM; i += 8) {
      r0 += sv[i + 0]; r1 += sv[i + 1]; r2 += sv[i + 2]; r3 += sv[i + 3];
      r4 += sv[i + 4]; r5 += sv[i + 5]; r6 += sv[i + 6]; r7 += sv[i + 7];
    }
    savg[tid] = (((r0 + r1) + (r2 + r3)) + ((r4 + r5) + (r6 + r7))) * 0.015625;
  }
  __syncthreads();
  if (tid == 0) {
    unsigned sm = 0u;
    for (int it = 0; it < KSTR; ++it) {
      double best = -1.0; int bi = 0;
      for (int s = 0; s < NSTRIPE; ++s)
        if (!((sm >> s) & 1u) && savg[s] > best) { best = savg[s]; bi = s; }
      sm |= (1u << bi);
    }
    sres3 = sm;
  }
  __syncthreads();
  const unsigned sm = sres3;

  const bool son = ((sm >> (tid >> 3)) & 1u) != 0u;
  double mv[8];
  unsigned act = 0u, cnt = 0u;
#pragma unroll
  for (int i = 0; i < 8; ++i) {
    mv[i] = v[tid * 8 + i];
    bool a = son && (mv[i] != 0.0);
    act |= (a ? 1u : 0u) << i;
    cnt += a ? 1u : 0u;
  }
  unsigned cincl = scan256_incl(cnt, sbuf, tid);
  unsigned pos = cincl - cnt;
  float* vrow = ovals + (size_t)row * KNEUR;
  int* irow = oidxs + (size_t)row * KNEUR;
#pragma unroll
  for (int i = 0; i < 8; ++i) {
    if ((act >> i) & 1u) {
      vrow[pos] = (float)mv[i];
      irow[pos] = tid * 8 + i;
      ++pos;
    }
  }
  if (tid == 255) onnz[row] = (int)cincl;
}

// ---------------------------------------------------------------------------
// Sparse decode (fp32): d[row,:] = relu(b3 + sum_j val_j * W3T[idx_j,:]).
// Epilogue writes d as bf16 hi|lo pairs (A2 [CH][2048]) for layer 4.
// ---------------------------------------------------------------------------
__global__ __launch_bounds__(256) void sparse_decode(
    const float* __restrict__ W3T, const void* __restrict__ b3v,
    const float* __restrict__ vals, const int* __restrict__ idxs,
    const int* __restrict__ nnz, unsigned short* __restrict__ A2,
    const int* __restrict__ dflag)
{
  __shared__ float sv[KNEUR];
  __shared__ int si[KNEUR];
  __shared__ int scnt;
  const int f = *dflag;
  const int tid = threadIdx.x;
  const int row = blockIdx.x;
  if (tid == 0) scnt = nnz[row];
  if (tid < KNEUR) {
    sv[tid] = vals[(size_t)row * KNEUR + tid];
    si[tid] = idxs[(size_t)row * KNEUR + tid];
  }
  __syncthreads();
  const int cnt = scnt;
  float4 acc;
  if (f) {
    const unsigned short* b3b = (const unsigned short*)b3v;
    acc.x = bf2f(b3b[4 * tid + 0]); acc.y = bf2f(b3b[4 * tid + 1]);
    acc.z = bf2f(b3b[4 * tid + 2]); acc.w = bf2f(b3b[4 * tid + 3]);
  } else {
    acc = ((const float4*)b3v)[tid];
  }
  for (int j = 0; j < cnt; ++j) {
    const float vv = sv[j];
    const float4 w = ((const float4*)(W3T + (size_t)si[j] * INTER))[tid];
    acc.x = fmaf(vv, w.x, acc.x);
    acc.y = fmaf(vv, w.y, acc.y);
    acc.z = fmaf(vv, w.z, acc.z);
    acc.w = fmaf(vv, w.w, acc.w);
  }
  acc.x = fmaxf(acc.x, 0.f); acc.y = fmaxf(acc.y, 0.f);
  acc.z = fmaxf(acc.z, 0.f); acc.w = fmaxf(acc.w, 0.f);

  ushort4 hi, lo;
  hi.x = f2bf_rn(acc.x); lo.x = f2bf_rn(acc.x - bf2f(hi.x));
  hi.y = f2bf_rn(acc.y); lo.y = f2bf_rn(acc.y - bf2f(hi.y));
  hi.z = f2bf_rn(acc.z); lo.z = f2bf_rn(acc.z - bf2f(hi.z));
  hi.w = f2bf_rn(acc.w); lo.w = f2bf_rn(acc.w - bf2f(hi.w));
  *(ushort4*)(A2 + (size_t)row * 2048 + 4 * tid) = hi;
  *(ushort4*)(A2 + (size_t)row * 2048 + 1024 + 4 * tid) = lo;
}

// ---------------------------------------------------------------------------
extern "C" void kernel_launch(void* const* d_in, const int* in_sizes, int n_in,
                              void* d_out, int out_size, void* d_ws, size_t ws_size,
                              hipStream_t stream)
{
  const void* x  = d_in[0];
  const void* W1 = d_in[1];
  const void* b1 = d_in[2];
  const void* W2 = d_in[3];
  const void* b2 = d_in[4];
  const void* W3 = d_in[5];
  const void* b3 = d_in[6];
  const void* W4 = d_in[7];
  const void* b4 = d_in[8];

  // layout: [flag 256B][W3T 8MB][B2 896*2048*2][W2d 16MB]
  //         [h64 CH*8K (A2 overlays)][c64 CH*16K][cv][ci][cn]
  const size_t W3T_BYTES = (size_t)CODE * INTER * 4;
  const size_t B2_BYTES  = (size_t)NPAD * 2048 * 2;
  const size_t W2D_BYTES = (size_t)CODE * INTER * 8;
  int CH = BATCH;
  while (CH > 128) {
    size_t need = 256 + W3T_BYTES + B2_BYTES + W2D_BYTES +
                  (size_t)CH * (8192 + 16384 + 256 + 256 + 4);
    if (need <= ws_size) break;
    CH >>= 1;
  }
  char*   w    = (char*)d_ws;
  int*    flag = (int*)w;
  float*  W3T  = (float*)(w + 256);
  unsigned short* B2w = (unsigned short*)(w + 256 + W3T_BYTES);
  double* W2d  = (double*)(w + 256 + W3T_BYTES + B2_BYTES);
  char*   p    = w + 256 + W3T_BYTES + B2_BYTES + W2D_BYTES;
  double* h64  = (double*)p;                                 // CH*1024 f64
  unsigned short* A2 = (unsigned short*)p;                   // overlays h64 (dead by then)
  double* c64  = (double*)(p + (size_t)CH * 8192);           // CH*2048 f64
  float*  cv   = (float*)(p + (size_t)CH * 24576);           // CH*64 f32
  int*    ci   = (int*)  (p + (size_t)CH * 24576 + (size_t)CH * 256);
  int*    cn   = (int*)  (p + (size_t)CH * 24576 + (size_t)CH * 512);

  detect_dtype<<<1, 256, 0, stream>>>((const unsigned*)W1, flag);
  transpose_w3<<<dim3(CODE / 32, INTER / 32), 256, 0, stream>>>(W3, W3T, flag);
  convert_w4<<<NPAD, 256, 0, stream>>>(W4, B2w, flag);
  convert_w2_f64<<<CODE, 256, 0, stream>>>(W2, W2d, flag);

  for (int r0 = 0; r0 < BATCH; r0 += CH) {
    // h = relu(x @ W1^T + b1) in f64   [CH, 1024], K=784  (MFMA f64, 64-tile)
    gemm_nt_f64_mfma<false><<<dim3(INTER / 64, CH / 64), 256, 0, stream>>>(
        x, W1, b1, h64, INTER, IN_DIM, r0, flag);

    // c = relu(h @ W2^T + b2) in f64   [CH, 2048], K=1024  (v2: 64x128 DMA MFMA)
    gemm2_f64_v2<<<dim3(CODE / 128, CH / 64), 256, 0, stream>>>(
        h64, W2d, b2, c64, flag);

    // exact top-64 + stripe top-4 on f64 values -> compact sparse code
    topk_compact_f64<<<CH, 256, 0, stream>>>(c64, cv, ci, cn);

    // d = relu(c_sparse @ W3^T + b3) -> bf16 hi|lo split (overlays h64)
    sparse_decode<<<CH, 256, 0, stream>>>(W3T, b3, cv, ci, cn, A2, flag);

    // out[r0:r0+CH] = relu(d @ W4^T + b4) via bf16 split-K MFMA, f32 out
    gemm_l4_bf16<<<dim3(NPAD / 128, CH / 128), 256, 0, stream>>>(
        A2, B2w, b4, (float*)d_out, r0, flag);
  }
}

// Round 17
// 2066.485 us; speedup vs baseline: 1.3022x; 1.0032x over previous
//
#include <hip/hip_runtime.h>
#include <hip/hip_bf16.h>
#include <stdint.h>

typedef unsigned long long ull;
typedef double vd4 __attribute__((ext_vector_type(4)));
typedef __attribute__((ext_vector_type(8))) short short8;
typedef __attribute__((ext_vector_type(4))) float f32x4;

#define BATCH   16384
#define IN_DIM  784
#define INTER   1024
#define CODE    2048
#define NSTRIPE 32
#define SDIM    64
#define KNEUR   64
#define KSTR    4
#define NPAD    896   // 784 padded to 7*128 for the layer-4 MFMA tile grid

__device__ __forceinline__ float bf2f(unsigned short u) {
  return __uint_as_float(((unsigned)u) << 16);
}

// round-to-nearest-even f32 -> bf16 bits
__device__ __forceinline__ unsigned short f2bf_rn(float x) {
  unsigned u = __float_as_uint(x);
  u += 0x7FFFu + ((u >> 16) & 1u);
  return (unsigned short)(u >> 16);
}

// async global->LDS, 16B per lane (dest must be linear in lane order)
__device__ __forceinline__ void gld_lds16(const void* g, void* l) {
  __builtin_amdgcn_global_load_lds(
      (__attribute__((address_space(1))) void*)(g),
      (__attribute__((address_space(3))) void*)(l), 16, 0, 0);
}

// ---------------------------------------------------------------------------
// Input dtype detector (insurance): flag=1 => inputs are bf16.
// ---------------------------------------------------------------------------
__global__ void detect_dtype(const unsigned* __restrict__ w1raw, int* __restrict__ flag) {
  __shared__ unsigned cnt;
  if (threadIdx.x == 0) cnt = 0u;
  __syncthreads();
  unsigned c = 0;
  for (int i = threadIdx.x; i < 512; i += 256) {
    unsigned e = (w1raw[i] >> 7) & 0xFFu;
    if (e >= 100u && e <= 126u) ++c;
  }
  atomicAdd(&cnt, c);
  __syncthreads();
  if (threadIdx.x == 0) *flag = (cnt > 256u) ? 1 : 0;
}

// ---------------------------------------------------------------------------
// One-time: W2 [2048][1024] (f32 or bf16) -> f64.
// ---------------------------------------------------------------------------
__global__ __launch_bounds__(256) void convert_w2_f64(
    const void* __restrict__ W2v, double* __restrict__ W2d,
    const int* __restrict__ dflag)
{
  const int f = *dflag;
  const size_t base = (size_t)blockIdx.x * INTER + 4u * threadIdx.x;
  double v0, v1, v2, v3;
  if (f) {
    ushort4 r = *(const ushort4*)((const unsigned short*)W2v + base);
    v0 = (double)bf2f(r.x); v1 = (double)bf2f(r.y);
    v2 = (double)bf2f(r.z); v3 = (double)bf2f(r.w);
  } else {
    float4 r = *(const float4*)((const float*)W2v + base);
    v0 = r.x; v1 = r.y; v2 = r.z; v3 = r.w;
  }
  W2d[base + 0] = v0; W2d[base + 1] = v1;
  W2d[base + 2] = v2; W2d[base + 3] = v3;
}

// ---------------------------------------------------------------------------
// Layer-2 FP64 MFMA GEMM v2 (verified r10/r13: 571us, MfmaUtil 83%, occ 41%).
// BM=64, BN=128, BK=16, 256 thr / 4 waves, wave tile 32x64 (acc 64 regs).
// global_load_lds staging, XOR-swizzled source+read. Bitwise-exact C.
// ---------------------------------------------------------------------------
__global__ __launch_bounds__(256, 3) void gemm2_f64_v2(
    const double* __restrict__ A, const double* __restrict__ B,
    const void* __restrict__ biasv, double* __restrict__ C,
    const int* __restrict__ dflag)
{
  __shared__ double As[64 * 16];    // 8 KB
  __shared__ double Bs[128 * 16];   // 16 KB
  const int f = *dflag;
  const int tid  = threadIdx.x;
  const int lane = tid & 63;
  const int wave = tid >> 6;                  // 0..3
  const int wr = wave >> 1, wc = wave & 1;    // rows: wr*32, cols: wc*64
  const int lm = lane & 15, lq = lane >> 4;
  const int m0 = blockIdx.y * 64, n0 = blockIdx.x * 128;
  const int axor = (lm & 7) << 1;             // read-side k-xor (row&7 == lm&7)

  vd4 acc[2][4];
#pragma unroll
  for (int i = 0; i < 2; ++i)
#pragma unroll
    for (int j = 0; j < 4; ++j)
#pragma unroll
      for (int r = 0; r < 4; ++r) acc[i][j][r] = 0.0;

  for (int k0 = 0; k0 < INTER; k0 += 16) {
#pragma unroll
    for (int i = 0; i < 2; ++i) {
      const int c  = i * 256 + tid;
      const int m  = c >> 3;
      const int kk = ((c & 7) << 1) ^ ((m & 7) << 1);
      gld_lds16(A + (size_t)(m0 + m) * INTER + (k0 + kk), (char*)As + c * 16);
    }
#pragma unroll
    for (int i = 0; i < 4; ++i) {
      const int c  = i * 256 + tid;
      const int m  = c >> 3;
      const int kk = ((c & 7) << 1) ^ ((m & 7) << 1);
      gld_lds16(B + (size_t)(n0 + m) * INTER + (k0 + kk), (char*)Bs + c * 16);
    }
    __syncthreads();   // compiler drains vmcnt before s_barrier

#pragma unroll
    for (int ks = 0; ks < 4; ++ks) {
      const int kx = (ks * 4 + lq) ^ axor;
      double a[2], b[4];
      a[0] = As[(wr * 32 + lm) * 16 + kx];
      a[1] = As[(wr * 32 + 16 + lm) * 16 + kx];
#pragma unroll
      for (int j = 0; j < 4; ++j)
        b[j] = Bs[(wc * 64 + j * 16 + lm) * 16 + kx];
#pragma unroll
      for (int i = 0; i < 2; ++i)
#pragma unroll
        for (int j = 0; j < 4; ++j)
          acc[i][j] = __builtin_amdgcn_mfma_f64_16x16x4f64(a[i], b[j], acc[i][j], 0, 0, 0);
    }
    __syncthreads();
  }

  // epilogue: D col = lane&15, row = (lane>>4)*4 + reg
#pragma unroll
  for (int j = 0; j < 4; ++j) {
    const int col = n0 + wc * 64 + j * 16 + lm;
    const double bv = f ? (double)bf2f(((const unsigned short*)biasv)[col])
                        : (double)((const float*)biasv)[col];
#pragma unroll
    for (int i = 0; i < 2; ++i) {
      const int row = m0 + wr * 32 + i * 16 + lq * 4;
#pragma unroll
      for (int r = 0; r < 4; ++r)
        C[(size_t)(row + r) * CODE + col] = fmax(acc[i][j][r] + bv, 0.0);
    }
  }
}

// ---------------------------------------------------------------------------
// FP64 MFMA GEMM NT (layer 1): C = relu(A[arow0+m,:]·B[n,:] + bias[n]) f64.
// 64x64 tile, 4 waves. A/B converted inline (x is f32/bf16).
// LDS padded [16][65]: kills 4-way same-bank collisions of [16][64].
// ---------------------------------------------------------------------------
template<bool A_IS_F64>
__global__ __launch_bounds__(256) void gemm_nt_f64_mfma(
    const void* __restrict__ Av, const void* __restrict__ Bv,
    const void* __restrict__ biasv, double* __restrict__ C,
    int N, int K, int arow0, const int* __restrict__ dflag)
{
  __shared__ double As[16][65];   // [k][m], +1 pad
  __shared__ double Bs[16][65];   // [k][n], +1 pad
  const int f = *dflag;
  const int tid  = threadIdx.x;
  const int lane = tid & 63;
  const int wave = tid >> 6;            // 0..3
  const int wr = wave >> 1, wc = wave & 1;
  const int m0 = blockIdx.y * 64, n0 = blockIdx.x * 64;

  const int srow = tid >> 2;            // 0..63 staging row
  const int sk4  = (tid & 3) << 2;      // 0,4,8,12

  vd4 acc[2][2];
#pragma unroll
  for (int i = 0; i < 2; ++i)
#pragma unroll
    for (int j = 0; j < 2; ++j)
#pragma unroll
      for (int r = 0; r < 4; ++r) acc[i][j][r] = 0.0;

  const int lm = lane & 15;             // m/n within 16-tile
  const int lq = lane >> 4;             // k within 4-chunk

  for (int k0 = 0; k0 < K; k0 += 16) {
    // ---- stage A tile (64 rows x 16 k) ----
    if (A_IS_F64) {
      const double* Ap = (const double*)Av + (size_t)(arow0 + m0 + srow) * K + (k0 + sk4);
      As[sk4 + 0][srow] = Ap[0]; As[sk4 + 1][srow] = Ap[1];
      As[sk4 + 2][srow] = Ap[2]; As[sk4 + 3][srow] = Ap[3];
    } else if (f) {
      ushort4 t = *(const ushort4*)((const unsigned short*)Av +
                   (size_t)(arow0 + m0 + srow) * K + (k0 + sk4));
      As[sk4 + 0][srow] = (double)bf2f(t.x); As[sk4 + 1][srow] = (double)bf2f(t.y);
      As[sk4 + 2][srow] = (double)bf2f(t.z); As[sk4 + 3][srow] = (double)bf2f(t.w);
    } else {
      float4 t = *(const float4*)((const float*)Av +
                  (size_t)(arow0 + m0 + srow) * K + (k0 + sk4));
      As[sk4 + 0][srow] = (double)t.x; As[sk4 + 1][srow] = (double)t.y;
      As[sk4 + 2][srow] = (double)t.z; As[sk4 + 3][srow] = (double)t.w;
    }
    // ---- stage B tile (64 rows x 16 k) ----
    if (f) {
      ushort4 t = *(const ushort4*)((const unsigned short*)Bv +
                   (size_t)(n0 + srow) * K + (k0 + sk4));
      Bs[sk4 + 0][srow] = (double)bf2f(t.x); Bs[sk4 + 1][srow] = (double)bf2f(t.y);
      Bs[sk4 + 2][srow] = (double)bf2f(t.z); Bs[sk4 + 3][srow] = (double)bf2f(t.w);
    } else {
      float4 t = *(const float4*)((const float*)Bv +
                  (size_t)(n0 + srow) * K + (k0 + sk4));
      Bs[sk4 + 0][srow] = (double)t.x; Bs[sk4 + 1][srow] = (double)t.y;
      Bs[sk4 + 2][srow] = (double)t.z; Bs[sk4 + 3][srow] = (double)t.w;
    }
    __syncthreads();

#pragma unroll
    for (int ks = 0; ks < 4; ++ks) {
      const int kk = ks * 4 + lq;
      double a0 = As[kk][wr * 32 + lm];
      double a1 = As[kk][wr * 32 + 16 + lm];
      double b0 = Bs[kk][wc * 32 + lm];
      double b1 = Bs[kk][wc * 32 + 16 + lm];
      acc[0][0] = __builtin_amdgcn_mfma_f64_16x16x4f64(a0, b0, acc[0][0], 0, 0, 0);
      acc[0][1] = __builtin_amdgcn_mfma_f64_16x16x4f64(a0, b1, acc[0][1], 0, 0, 0);
      acc[1][0] = __builtin_amdgcn_mfma_f64_16x16x4f64(a1, b0, acc[1][0], 0, 0, 0);
      acc[1][1] = __builtin_amdgcn_mfma_f64_16x16x4f64(a1, b1, acc[1][1], 0, 0, 0);
    }
    __syncthreads();
  }

  // ---- epilogue: D col = lane&15, row = (lane>>4)*4 + reg ----
#pragma unroll
  for (int tc = 0; tc < 2; ++tc) {
    const int col = n0 + wc * 32 + tc * 16 + lm;
    const double bv = f ? (double)bf2f(((const unsigned short*)biasv)[col])
                        : (double)((const float*)biasv)[col];
#pragma unroll
    for (int tr = 0; tr < 2; ++tr) {
#pragma unroll
      for (int r = 0; r < 4; ++r) {
        const int row = m0 + wr * 32 + tr * 16 + lq * 4 + r;
        C[(size_t)row * N + col] = fmax(acc[tr][tc][r] + bv, 0.0);
      }
    }
  }
}

// ---------------------------------------------------------------------------
// One-time: split W4 [784][1024] (f32 or bf16) into bf16 hi|lo pairs,
// padded to 896 rows (pad rows zeroed).
// ---------------------------------------------------------------------------
__global__ __launch_bounds__(256) void convert_w4(
    const void* __restrict__ W4v, unsigned short* __restrict__ B2,
    const int* __restrict__ dflag)
{
  const int f = *dflag;
  const int n = blockIdx.x;            // 0..895
  const int t = threadIdx.x;           // 4 elems each
  ushort4 hi, lo;
  hi.x = hi.y = hi.z = hi.w = 0;
  lo.x = lo.y = lo.z = lo.w = 0;
  if (n < IN_DIM) {
    float v0, v1, v2, v3;
    if (f) {
      ushort4 r = *(const ushort4*)((const unsigned short*)W4v + (size_t)n * INTER + 4 * t);
      v0 = bf2f(r.x); v1 = bf2f(r.y); v2 = bf2f(r.z); v3 = bf2f(r.w);
    } else {
      float4 r = *(const float4*)((const float*)W4v + (size_t)n * INTER + 4 * t);
      v0 = r.x; v1 = r.y; v2 = r.z; v3 = r.w;
    }
    hi.x = f2bf_rn(v0); lo.x = f2bf_rn(v0 - bf2f(hi.x));
    hi.y = f2bf_rn(v1); lo.y = f2bf_rn(v1 - bf2f(hi.y));
    hi.z = f2bf_rn(v2); lo.z = f2bf_rn(v2 - bf2f(hi.z));
    hi.w = f2bf_rn(v3); lo.w = f2bf_rn(v3 - bf2f(hi.w));
  }
  *(ushort4*)(B2 + (size_t)n * 2048 + 4 * t) = hi;
  *(ushort4*)(B2 + (size_t)n * 2048 + 1024 + 4 * t) = lo;
}

// ---------------------------------------------------------------------------
// Layer-4 GEMM via bf16 MFMA with hi/lo split-K emulation (~f32 accuracy).
// 128x128 tile, BK=32, 4 waves, 16x16x32 MFMA, global_load_lds staging.
// ---------------------------------------------------------------------------
__global__ __launch_bounds__(256) void gemm_l4_bf16(
    const unsigned short* __restrict__ A2,   // [CH][2048] hi|lo
    const unsigned short* __restrict__ B2,   // [896][2048] hi|lo (pad zeroed)
    const void* __restrict__ biasv, float* __restrict__ Cout,
    int crow0, const int* __restrict__ dflag)
{
  __shared__ unsigned short As[128 * 32];    // 8 KB, rows of 32 bf16 (64 B)
  __shared__ unsigned short Bs[128 * 32];    // 8 KB
  const int f = *dflag;
  const int tid  = threadIdx.x;
  const int lane = tid & 63;
  const int wave = tid >> 6;                 // 0..3
  const int wr = wave >> 1, wc = wave & 1;   // 2x2 wave grid of 64x64
  const int lm = lane & 15, lg = lane >> 4;
  const int m0 = blockIdx.y * 128, n0 = blockIdx.x * 128;

  f32x4 acc[4][4];
#pragma unroll
  for (int i = 0; i < 4; ++i)
#pragma unroll
    for (int j = 0; j < 4; ++j)
#pragma unroll
      for (int r = 0; r < 4; ++r) acc[i][j][r] = 0.0f;

  const char* a2b = (const char*)A2;
  const char* b2b = (const char*)B2;

  for (int kt = 0; kt < 96; ++kt) {
    const int s   = kt >> 5;                 // segment 0,1,2
    const int kin = (kt & 31) << 5;          // 0..992
    const int ka  = ((s == 1) ? 1024 : 0) + kin;   // A half: lo only in seg 1
    const int kb  = ((s == 2) ? 1024 : 0) + kin;   // B half: lo only in seg 2
#pragma unroll
    for (int i = 0; i < 2; ++i) {
      const int c   = i * 256 + tid;         // chunk id
      const int row = c >> 2;                // 0..127
      const int cb  = (c & 3) * 16;          // byte within 64B row
      gld_lds16(a2b + ((size_t)(m0 + row) * 4096 + (size_t)(ka * 2 + cb)),
                (char*)As + c * 16);
      gld_lds16(b2b + ((size_t)(n0 + row) * 4096 + (size_t)(kb * 2 + cb)),
                (char*)Bs + c * 16);
    }
    __syncthreads();                         // drains vmcnt before barrier

    short8 a[4], b[4];
#pragma unroll
    for (int i = 0; i < 4; ++i) {
      a[i] = *(const short8*)((const char*)As + (wr * 64 + i * 16 + lm) * 64 + lg * 16);
      b[i] = *(const short8*)((const char*)Bs + (wc * 64 + i * 16 + lm) * 64 + lg * 16);
    }
#pragma unroll
    for (int i = 0; i < 4; ++i)
#pragma unroll
      for (int j = 0; j < 4; ++j)
        acc[i][j] = __builtin_amdgcn_mfma_f32_16x16x32_bf16(a[i], b[j], acc[i][j], 0, 0, 0);
    __syncthreads();
  }

  // ---- epilogue: D col = lane&15, row = (lane>>4)*4 + reg ----
#pragma unroll
  for (int j = 0; j < 4; ++j) {
    const int col = n0 + wc * 64 + j * 16 + lm;
    if (col < IN_DIM) {
      const float bv = f ? bf2f(((const unsigned short*)biasv)[col])
                         : ((const float*)biasv)[col];
#pragma unroll
      for (int i = 0; i < 4; ++i) {
        const int row0 = crow0 + m0 + wr * 64 + i * 16 + lg * 4;
#pragma unroll
        for (int r = 0; r < 4; ++r)
          Cout[(size_t)(row0 + r) * IN_DIM + col] = fmaxf(acc[i][j][r] + bv, 0.0f);
      }
    }
  }
}

// ---------------------------------------------------------------------------
// Transpose W3 [1024][2048] -> W3T fp32 [2048][1024] for coalesced gather.
// ---------------------------------------------------------------------------
__global__ __launch_bounds__(256) void transpose_w3(
    const void* __restrict__ W3v, float* __restrict__ W3T, const int* __restrict__ dflag)
{
  __shared__ float tile[32][33];
  const int f = *dflag;
  const int tx = threadIdx.x & 31, ty = threadIdx.x >> 5;  // 32 x 8
  const int c0 = blockIdx.x * 32;
  const int r0 = blockIdx.y * 32;
#pragma unroll
  for (int i = 0; i < 32; i += 8) {
    size_t off = (size_t)(r0 + ty + i) * CODE + (c0 + tx);
    tile[ty + i][tx] = f ? bf2f(((const unsigned short*)W3v)[off])
                         : ((const float*)W3v)[off];
  }
  __syncthreads();
#pragma unroll
  for (int i = 0; i < 32; i += 8)
    W3T[(size_t)(c0 + ty + i) * INTER + (r0 + tx)] = tile[tx][ty + i];
}

// ---------------------------------------------------------------------------
// Block scans (256 threads) — wave-level shfl scans (verified r13).
// Side-effects preserved: buf[tid] holds this thread's scan value on return.
// ---------------------------------------------------------------------------
__device__ __forceinline__ unsigned scan256_incl(unsigned x, unsigned* buf, int tid) {
  const int lane = tid & 63, wave = tid >> 6;
#pragma unroll
  for (int off = 1; off < 64; off <<= 1) {
    unsigned y = __shfl_up(x, off, 64);
    if (lane >= off) x += y;
  }
  __syncthreads();                       // protect buf from previous use
  if (lane == 63) buf[wave] = x;         // wave totals -> buf[0..3]
  __syncthreads();
  unsigned add = 0u;
  if (wave > 0) add += buf[0];
  if (wave > 1) add += buf[1];
  if (wave > 2) add += buf[2];
  x += add;
  __syncthreads();                       // before overwriting buf[0..3]
  buf[tid] = x;
  __syncthreads();
  return x;
}
__device__ __forceinline__ unsigned scan256_suffix(unsigned x, unsigned* buf, int tid) {
  const int lane = tid & 63, wave = tid >> 6;
#pragma unroll
  for (int off = 1; off < 64; off <<= 1) {
    unsigned y = __shfl_down(x, off, 64);
    if (lane + off < 64) x += y;
  }
  __syncthreads();
  if (lane == 0) buf[wave] = x;          // wave totals (suffix) -> buf[0..3]
  __syncthreads();
  unsigned add = 0u;
  if (wave < 3) add += buf[3];
  if (wave < 2) add += buf[2];
  if (wave < 1) add += buf[1];
  x += add;
  __syncthreads();
  buf[tid] = x;
  __syncthreads();
  return x;
}

// ---------------------------------------------------------------------------
// FP64 per-row top-64 radix select (44-bit key, ties lowest-index-first),
// fp64 stripe means, top-4 stripes, compaction to (f32 val, idx, nnz).
// ---------------------------------------------------------------------------
__global__ __launch_bounds__(256) void topk_compact_f64(
    const double* __restrict__ C, float* __restrict__ ovals,
    int* __restrict__ oidxs, int* __restrict__ onnz)
{
  __shared__ double v[CODE];            // 16 KB
  __shared__ unsigned hist[CODE];       // 8 KB
  __shared__ unsigned sbuf[256];
  __shared__ unsigned sres0, sres1, sres3;
  __shared__ int sres2;
  __shared__ double savg[NSTRIPE];
  const int tid = threadIdx.x;
  const int row = blockIdx.x;

  const double2* c2 = (const double2*)(C + (size_t)row * CODE);
#pragma unroll
  for (int i = 0; i < 4; ++i)
    ((double2*)v)[tid + 256 * i] = c2[tid + 256 * i];
  __syncthreads();

  ull u[8];
#pragma unroll
  for (int i = 0; i < 8; ++i) u[i] = __double_as_longlong(v[tid * 8 + i]);

  const int shifts[4] = {52, 41, 30, 19};
  unsigned kr = KNEUR;
  ull prefix = 0ull, pmask = 0ull;
  bool tz = false;

  for (int p = 0; p < 4; ++p) {
    const int sh = shifts[p];
    for (int i = tid; i < CODE; i += 256) hist[i] = 0u;
    __syncthreads();
#pragma unroll
    for (int i = 0; i < 8; ++i)
      if (u[i] != 0ull && (u[i] & pmask) == prefix)
        atomicAdd(&hist[(unsigned)((u[i] >> sh) & 2047ull)], 1u);
    __syncthreads();
    unsigned csum = 0u;
#pragma unroll
    for (int j = 0; j < 8; ++j) csum += hist[tid * 8 + j];
    unsigned sc = scan256_suffix(csum, sbuf, tid);
    unsigned scn = (tid < 255) ? sbuf[tid + 1] : 0u;
    if (p == 0 && tid == 0) sres2 = (sc < kr) ? 1 : 0;
    if (sc >= kr && scn < kr) {
      unsigned cum = scn;
      for (int b = 7; b >= 0; --b) {
        unsigned hb = hist[tid * 8 + b];
        if (cum + hb >= kr) { sres0 = (unsigned)(tid * 8 + b); sres1 = cum; break; }
        cum += hb;
      }
    }
    __syncthreads();
    if (p == 0 && sres2) { tz = true; break; }
    kr -= sres1;
    prefix |= ((ull)sres0) << sh;
    pmask  |= 2047ull << sh;
    __syncthreads();
  }

  const ull tkey = tz ? 0ull : (prefix >> 19);

  unsigned gt = 0u, eq = 0u;
#pragma unroll
  for (int i = 0; i < 8; ++i) {
    ull k = u[i] >> 19;
    gt += (k > tkey) ? 1u : 0u;
    eq += (k == tkey) ? 1u : 0u;
  }
  unsigned eqincl = scan256_incl(eq, sbuf, tid);
  unsigned eqbase = eqincl - eq;
  (void)scan256_incl(gt, sbuf, tid);
  unsigned total_gt = sbuf[255];
  unsigned need_eq = KNEUR - total_gt;
  unsigned er = eqbase;
#pragma unroll
  for (int i = 0; i < 8; ++i) {
    ull k = u[i] >> 19;
    bool sel = (k > tkey);
    if (k == tkey) { sel = (er < need_eq); ++er; }
    if (!sel) v[tid * 8 + i] = 0.0;
  }
  __syncthreads();

  if (tid < NSTRIPE) {
    const double* sv = v + tid * SDIM;
    double r0 = sv[0], r1 = sv[1], r2 = sv[2], r3 = sv[3],
           r4 = sv[4], r5 = sv[5], r6 = sv[6], r7 = sv[7];
    for (int i = 8; i < SDIM; i += 8) {
      r0 += sv[i + 0]; r1 += sv[i + 1]; r2 += sv[i + 2]; r3 += sv[i + 3];
      r4 += sv[i + 4]; r5 += sv[i + 5]; r6 += sv[i + 6]; r7 += sv[i + 7];
    }
    savg[tid] = (((r0 + r1) + (r2 + r3)) + ((r4 + r5) + (r6 + r7))) * 0.015625;
  }
  __syncthreads();
  if (tid == 0) {
    unsigned sm = 0u;
    for (int it = 0; it < KSTR; ++it) {
      double best = -1.0; int bi = 0;
      for (int s = 0; s < NSTRIPE; ++s)
        if (!((sm >> s) & 1u) && savg[s] > best) { best = savg[s]; bi = s; }
      sm |= (1u << bi);
    }
    sres3 = sm;
  }
  __syncthreads();
  const unsigned sm = sres3;

  const bool son = ((sm >> (tid >> 3)) & 1u) != 0u;
  double mv[8];
  unsigned act = 0u, cnt = 0u;
#pragma unroll
  for (int i = 0; i < 8; ++i) {
    mv[i] = v[tid * 8 + i];
    bool a = son && (mv[i] != 0.0);
    act |= (a ? 1u : 0u) << i;
    cnt += a ? 1u : 0u;
  }
  unsigned cincl = scan256_incl(cnt, sbuf, tid);
  unsigned pos = cincl - cnt;
  float* vrow = ovals + (size_t)row * KNEUR;
  int* irow = oidxs + (size_t)row * KNEUR;
#pragma unroll
  for (int i = 0; i < 8; ++i) {
    if ((act >> i) & 1u) {
      vrow[pos] = (float)mv[i];
      irow[pos] = tid * 8 + i;
      ++pos;
    }
  }
  if (tid == 255) onnz[row] = (int)cincl;
}

// ---------------------------------------------------------------------------
// Sparse decode (fp32): d[row,:] = relu(b3 + sum_j val_j * W3T[idx_j,:]).
// Epilogue writes d as bf16 hi|lo pairs (A2 [CH][2048]) for layer 4.
// ---------------------------------------------------------------------------
__global__ __launch_bounds__(256) void sparse_decode(
    const float* __restrict__ W3T, const void* __restrict__ b3v,
    const float* __restrict__ vals, const int* __restrict__ idxs,
    const int* __restrict__ nnz, unsigned short* __restrict__ A2,
    const int* __restrict__ dflag)
{
  __shared__ float sv[KNEUR];
  __shared__ int si[KNEUR];
  __shared__ int scnt;
  const int f = *dflag;
  const int tid = threadIdx.x;
  const int row = blockIdx.x;
  if (tid == 0) scnt = nnz[row];
  if (tid < KNEUR) {
    sv[tid] = vals[(size_t)row * KNEUR + tid];
    si[tid] = idxs[(size_t)row * KNEUR + tid];
  }
  __syncthreads();
  const int cnt = scnt;
  float4 acc;
  if (f) {
    const unsigned short* b3b = (const unsigned short*)b3v;
    acc.x = bf2f(b3b[4 * tid + 0]); acc.y = bf2f(b3b[4 * tid + 1]);
    acc.z = bf2f(b3b[4 * tid + 2]); acc.w = bf2f(b3b[4 * tid + 3]);
  } else {
    acc = ((const float4*)b3v)[tid];
  }
  for (int j = 0; j < cnt; ++j) {
    const float vv = sv[j];
    const float4 w = ((const float4*)(W3T + (size_t)si[j] * INTER))[tid];
    acc.x = fmaf(vv, w.x, acc.x);
    acc.y = fmaf(vv, w.y, acc.y);
    acc.z = fmaf(vv, w.z, acc.z);
    acc.w = fmaf(vv, w.w, acc.w);
  }
  acc.x = fmaxf(acc.x, 0.f); acc.y = fmaxf(acc.y, 0.f);
  acc.z = fmaxf(acc.z, 0.f); acc.w = fmaxf(acc.w, 0.f);

  ushort4 hi, lo;
  hi.x = f2bf_rn(acc.x); lo.x = f2bf_rn(acc.x - bf2f(hi.x));
  hi.y = f2bf_rn(acc.y); lo.y = f2bf_rn(acc.y - bf2f(hi.y));
  hi.z = f2bf_rn(acc.z); lo.z = f2bf_rn(acc.z - bf2f(hi.z));
  hi.w = f2bf_rn(acc.w); lo.w = f2bf_rn(acc.w - bf2f(hi.w));
  *(ushort4*)(A2 + (size_t)row * 2048 + 4 * tid) = hi;
  *(ushort4*)(A2 + (size_t)row * 2048 + 1024 + 4 * tid) = lo;
}

// ---------------------------------------------------------------------------
extern "C" void kernel_launch(void* const* d_in, const int* in_sizes, int n_in,
                              void* d_out, int out_size, void* d_ws, size_t ws_size,
                              hipStream_t stream)
{
  const void* x  = d_in[0];
  const void* W1 = d_in[1];
  const void* b1 = d_in[2];
  const void* W2 = d_in[3];
  const void* b2 = d_in[4];
  const void* W3 = d_in[5];
  const void* b3 = d_in[6];
  const void* W4 = d_in[7];
  const void* b4 = d_in[8];

  // layout: [flag 256B][W3T 8MB][B2 896*2048*2][W2d 16MB]
  //         [h64 CH*8K (A2 overlays)][c64 CH*16K][cv][ci][cn]
  const size_t W3T_BYTES = (size_t)CODE * INTER * 4;
  const size_t B2_BYTES  = (size_t)NPAD * 2048 * 2;
  const size_t W2D_BYTES = (size_t)CODE * INTER * 8;
  int CH = BATCH;
  while (CH > 128) {
    size_t need = 256 + W3T_BYTES + B2_BYTES + W2D_BYTES +
                  (size_t)CH * (8192 + 16384 + 256 + 256 + 4);
    if (need <= ws_size) break;
    CH >>= 1;
  }
  char*   w    = (char*)d_ws;
  int*    flag = (int*)w;
  float*  W3T  = (float*)(w + 256);
  unsigned short* B2w = (unsigned short*)(w + 256 + W3T_BYTES);
  double* W2d  = (double*)(w + 256 + W3T_BYTES + B2_BYTES);
  char*   p    = w + 256 + W3T_BYTES + B2_BYTES + W2D_BYTES;
  double* h64  = (double*)p;                                 // CH*1024 f64
  unsigned short* A2 = (unsigned short*)p;                   // overlays h64 (dead by then)
  double* c64  = (double*)(p + (size_t)CH * 8192);           // CH*2048 f64
  float*  cv   = (float*)(p + (size_t)CH * 24576);           // CH*64 f32
  int*    ci   = (int*)  (p + (size_t)CH * 24576 + (size_t)CH * 256);
  int*    cn   = (int*)  (p + (size_t)CH * 24576 + (size_t)CH * 512);

  detect_dtype<<<1, 256, 0, stream>>>((const unsigned*)W1, flag);
  transpose_w3<<<dim3(CODE / 32, INTER / 32), 256, 0, stream>>>(W3, W3T, flag);
  convert_w4<<<NPAD, 256, 0, stream>>>(W4, B2w, flag);
  convert_w2_f64<<<CODE, 256, 0, stream>>>(W2, W2d, flag);

  for (int r0 = 0; r0 < BATCH; r0 += CH) {
    // h = relu(x @ W1^T + b1) in f64   [CH, 1024], K=784  (MFMA f64, 64-tile)
    gemm_nt_f64_mfma<false><<<dim3(INTER / 64, CH / 64), 256, 0, stream>>>(
        x, W1, b1, h64, INTER, IN_DIM, r0, flag);

    // c = relu(h @ W2^T + b2) in f64   [CH, 2048], K=1024  (v2: 64x128 DMA MFMA)
    gemm2_f64_v2<<<dim3(CODE / 128, CH / 64), 256, 0, stream>>>(
        h64, W2d, b2, c64, flag);

    // exact top-64 + stripe top-4 on f64 values -> compact sparse code
    topk_compact_f64<<<CH, 256, 0, stream>>>(c64, cv, ci, cn);

    // d = relu(c_sparse @ W3^T + b3) -> bf16 hi|lo split (overlays h64)
    sparse_decode<<<CH, 256, 0, stream>>>(W3T, b3, cv, ci, cn, A2, flag);

    // out[r0:r0+CH] = relu(d @ W4^T + b4) via bf16 split-K MFMA, f32 out
    gemm_l4_bf16<<<dim3(NPAD / 128, CH / 128), 256, 0, stream>>>(
        A2, B2w, b4, (float*)d_out, r0, flag);
  }
}